// Round 7
// baseline (245.677 us; speedup 1.0000x reference)
//
#include <hip/hip_runtime.h>
#include <hip/hip_bf16.h>
#include <math.h>

// ---------------------------------------------------------------------------
// GatedCrossAttentionBlock on MI355X (gfx950), bf16-MFMA implementation. R7.
//
// Pipeline (5 launches):
//   1. stage1   : weight transpose + bias concat + LN(cache) + build_v(+LN)
//   2. gemm_qg  : merged N=384: qb=(vn@Wv+bv)*scale*log2e | ghb=relu(v@Wg1+bg1)
//   3. gemm kval: cn@[Wc|Wvc]+bias -> kb bf16 + valTb bf16 (b,h,d,s)
//   4. attn     : 64 t/block, 2 waves x 32 t  -> 2144 blocks (8.4/CU, real
//                 TLP this time). Single-buffer LDS + register prefetch,
//                 flat fragment-order K/V (conflict-free reads), exp2-domain
//                 softmax, bias in MFMA C-op, denom via P x ones; coalesced
//                 ob epilogue through per-wave LDS tile -> full 64B lines.
//   5. gemm_out : dual GEMM; out = vT + tanh(gate)*delta via LDS transpose
// ---------------------------------------------------------------------------

typedef __attribute__((ext_vector_type(8))) short short8;
typedef __attribute__((ext_vector_type(4))) float f32x4;
typedef __hip_bfloat16 bf16;

#define T_TOK 8525
#define S_TOK 1024
#define CDIM  256
#define NHEAD 8
#define BSZ   2

static __device__ __forceinline__ f32x4 mfma16(short8 a, short8 b, f32x4 c) {
  return __builtin_amdgcn_mfma_f32_16x16x32_bf16(a, b, c, 0, 0, 0);
}

static __device__ __forceinline__ float fexp2(float x) {
#if __has_builtin(__builtin_amdgcn_exp2f)
  return __builtin_amdgcn_exp2f(x);
#else
  return exp2f(x);
#endif
}

static __device__ __forceinline__ unsigned int pack_bf16(float a, float b) {
#if __has_builtin(__builtin_amdgcn_perm)
  return __builtin_amdgcn_perm(__float_as_uint(b), __float_as_uint(a), 0x07060302u);
#else
  return (__float_as_uint(a) >> 16) | (__float_as_uint(b) & 0xFFFF0000u);
#endif
}

// ---------------------------------------------------------------------------
// 1. stage1: blocks 0..79 weight tiles, 80 bias concat, 81..592 LN(cache),
//            593.. build_v (+LN(v)). LDS aliased: both paths use 4160 floats.
// ---------------------------------------------------------------------------
__global__ __launch_bounds__(256) void stage1(
    const float* __restrict__ q0, const float* __restrict__ q1,
    const float* __restrict__ q2, const float* __restrict__ q3,
    const float* __restrict__ q4,
    const float* __restrict__ Wv, const float* __restrict__ Wc,
    const float* __restrict__ Wvc, const float* __restrict__ Wo,
    const float* __restrict__ Wg1, const float* __restrict__ Wg2,
    const float* __restrict__ bv, const float* __restrict__ bg1,
    const float* __restrict__ bc, const float* __restrict__ bvc,
    const float* __restrict__ cache, const float* __restrict__ ln_c_g,
    const float* __restrict__ ln_c_b, const float* __restrict__ ln_v_g,
    const float* __restrict__ ln_v_b,
    bf16* __restrict__ WqgT, bf16* __restrict__ WcvcT, bf16* __restrict__ WoT,
    bf16* __restrict__ Wg2T, float* __restrict__ biasCV,
    float* __restrict__ biasQG, bf16* __restrict__ cnb,
    float* __restrict__ vT, bf16* __restrict__ vb, bf16* __restrict__ vnb) {
  __shared__ float sm[4160];
  const int bid = blockIdx.x, tid = threadIdx.x;
  if (bid == 80) {
    biasCV[tid] = bc[tid];
    biasCV[tid + 256] = bvc[tid];
    biasQG[tid] = bv[tid];
    if (tid < 128) biasQG[256 + tid] = bg1[tid];
    return;
  }
  if (bid > 80 && bid < 593) {  // LN over cache rows
    int lane = tid & 63;
    int row = (bid - 81) * 4 + (tid >> 6);
    const float* x = cache + (size_t)row * CDIM;
    float v0 = x[lane], v1 = x[lane + 64], v2 = x[lane + 128], v3 = x[lane + 192];
    float s = v0 + v1 + v2 + v3;
    float s2 = v0 * v0 + v1 * v1 + v2 * v2 + v3 * v3;
#pragma unroll
    for (int off = 1; off < 64; off <<= 1) {
      s += __shfl_xor(s, off);
      s2 += __shfl_xor(s2, off);
    }
    float mean = s * (1.f / 256.f);
    float var = s2 * (1.f / 256.f) - mean * mean;
    float rstd = rsqrtf(var + 1e-5f);
    bf16* y = cnb + (size_t)row * CDIM;
    y[lane] = __float2bfloat16((v0 - mean) * rstd * ln_c_g[lane] + ln_c_b[lane]);
    y[lane + 64] = __float2bfloat16((v1 - mean) * rstd * ln_c_g[lane + 64] + ln_c_b[lane + 64]);
    y[lane + 128] = __float2bfloat16((v2 - mean) * rstd * ln_c_g[lane + 128] + ln_c_b[lane + 128]);
    y[lane + 192] = __float2bfloat16((v3 - mean) * rstd * ln_c_g[lane + 192] + ln_c_b[lane + 192]);
    return;
  }
  if (bid < 80) {  // weight transpose tiles
    float (*tl)[65] = (float(*)[65])sm;  // [64 n][65 k]
    const float* W; bf16* WT; int K, N, local;
    if (bid < 16)      { W = Wv;  WT = WqgT;           K = 256; N = 256; local = bid; }
    else if (bid < 32) { W = Wc;  WT = WcvcT;          K = 256; N = 256; local = bid - 16; }
    else if (bid < 48) { W = Wvc; WT = WcvcT + 65536;  K = 256; N = 256; local = bid - 32; }
    else if (bid < 64) { W = Wo;  WT = WoT;            K = 256; N = 256; local = bid - 48; }
    else if (bid < 72) { W = Wg1; WT = WqgT + 65536;   K = 256; N = 128; local = bid - 64; }
    else               { W = Wg2; WT = Wg2T;           K = 128; N = 256; local = bid - 72; }
    const int ktiles = K >> 6;
    const int K0 = (local % ktiles) * 64, N0 = (local / ktiles) * 64;
    const int kk = tid >> 4, n4 = (tid & 15) * 4;
#pragma unroll
    for (int i = 0; i < 4; ++i) {
      int k = kk + 16 * i;
      float4 w4 = *(const float4*)&W[(size_t)(K0 + k) * N + N0 + n4];
      tl[n4 + 0][k] = w4.x; tl[n4 + 1][k] = w4.y;
      tl[n4 + 2][k] = w4.z; tl[n4 + 3][k] = w4.w;
    }
    __syncthreads();
    const int nn = tid >> 4, k4 = (tid & 15) * 4;
#pragma unroll
    for (int i = 0; i < 4; ++i) {
      int n = nn + 16 * i;
      bf16 o[4] __attribute__((aligned(8)));
#pragma unroll
      for (int j = 0; j < 4; ++j) o[j] = __float2bfloat16(tl[n][k4 + j]);
      *(uint2*)&WT[(size_t)(N0 + n) * K + K0 + k4] = *(uint2*)o;
    }
    return;
  }
  // ------- build_v path -------
  constexpr int HW[5] = {6400, 1600, 400, 100, 25};
  constexpr int TST[5] = {0, 6400, 8000, 8400, 8500};
  constexpr int T16[5] = {0, 400, 500, 525, 532};
  float (*tile)[260] = (float(*)[260])sm;  // [16 p][260 c]
  const int bb = bid - 593;
  const int tileid = bb % 534, b = bb / 534;
  int lvl = 0;
#pragma unroll
  for (int i = 1; i < 5; ++i) if (tileid >= T16[i]) lvl = i;
  const int p0 = (tileid - T16[lvl]) * 16;
  const int hw = HW[lvl];
  const float* src = ((lvl == 0) ? q0 : (lvl == 1) ? q1 : (lvl == 2) ? q2
                      : (lvl == 3) ? q3 : q4) + (size_t)b * CDIM * hw;
  const int pl = tid & 15, cb = tid >> 4;
  const int pg = p0 + pl;
#pragma unroll
  for (int i = 0; i < 16; ++i) {
    int c = cb + 16 * i;
    tile[pl][c] = (pg < hw) ? src[(size_t)c * hw + pg] : 0.f;
  }
  __syncthreads();
  if (pg < hw) {
    int tglob = TST[lvl] + pg;
#pragma unroll
    for (int i = 0; i < 16; ++i) {
      int c = cb + 16 * i;
      vT[((size_t)b * CDIM + c) * T_TOK + tglob] = tile[pl][c];
    }
  }
  const int lane = tid & 63, w = tid >> 6;
#pragma unroll
  for (int rr = 0; rr < 4; ++rr) {
    int row = w * 4 + rr;
    int p = p0 + row;
    if (p >= hw) continue;
    float x0 = tile[row][lane], x1 = tile[row][lane + 64],
          x2 = tile[row][lane + 128], x3 = tile[row][lane + 192];
    float s = x0 + x1 + x2 + x3;
    float s2 = x0 * x0 + x1 * x1 + x2 * x2 + x3 * x3;
#pragma unroll
    for (int off = 1; off < 64; off <<= 1) {
      s += __shfl_xor(s, off);
      s2 += __shfl_xor(s2, off);
    }
    float mean = s * (1.f / 256.f);
    float var = s2 * (1.f / 256.f) - mean * mean;
    float rstd = rsqrtf(var + 1e-5f);
    size_t base = ((size_t)b * T_TOK + TST[lvl] + p) * CDIM;
    float xs[4] = {x0, x1, x2, x3};
#pragma unroll
    for (int j = 0; j < 4; ++j) {
      int c = lane + 64 * j;
      float x = xs[j];
      vb[base + c] = __float2bfloat16(x);
      vnb[base + c] = __float2bfloat16((x - mean) * rstd * ln_v_g[c] + ln_v_b[c]);
    }
  }
}

// ---------------------------------------------------------------------------
// 2. merged q|gh GEMM: N=384. n0<256 -> qb (A=vnb, scale); else ghb (A=vb,
//    relu). K=256. Block 128m x 64n, 4 waves.
// ---------------------------------------------------------------------------
__global__ __launch_bounds__(256) void gemm_qg(
    const bf16* __restrict__ vnb, const bf16* __restrict__ vb,
    const bf16* __restrict__ WqgT, const float* __restrict__ biasQG,
    bf16* __restrict__ qb, bf16* __restrict__ ghb, int M) {
  __shared__ __align__(16) bf16 Asl[128][136];
  __shared__ __align__(16) bf16 Bsl[64][136];
  const int tid = threadIdx.x;
  const int wave = tid >> 6, lane = tid & 63, quad = lane >> 4, l15 = lane & 15;
  const int m0 = blockIdx.y * 128;
  const int n0 = blockIdx.x * 64;
  const bf16* A = (n0 < 256) ? vnb : vb;
  f32x4 acc[2][4];
#pragma unroll
  for (int i = 0; i < 2; ++i)
#pragma unroll
    for (int j = 0; j < 4; ++j) acc[i][j] = (f32x4){0.f, 0.f, 0.f, 0.f};

  for (int k0 = 0; k0 < 256; k0 += 128) {
    __syncthreads();
#pragma unroll
    for (int c = 0; c < 8; ++c) {
      int chunk = c * 256 + tid;
      int row = chunk >> 4, col = (chunk & 15) * 8;
      int gr = m0 + row;
      if (gr >= M) gr = M - 1;
      *(uint4*)&Asl[row][col] = *(const uint4*)&A[(size_t)gr * 256 + k0 + col];
    }
#pragma unroll
    for (int c = 0; c < 4; ++c) {
      int chunk = c * 256 + tid;
      int row = chunk >> 4, col = (chunk & 15) * 8;
      *(uint4*)&Bsl[row][col] = *(const uint4*)&WqgT[(size_t)(n0 + row) * 256 + k0 + col];
    }
    __syncthreads();
#pragma unroll
    for (int kk = 0; kk < 128; kk += 32) {
      short8 af0 = *(const short8*)&Asl[wave * 32 + l15][kk + quad * 8];
      short8 af1 = *(const short8*)&Asl[wave * 32 + 16 + l15][kk + quad * 8];
      short8 bf0 = *(const short8*)&Bsl[l15][kk + quad * 8];
      short8 bf1 = *(const short8*)&Bsl[16 + l15][kk + quad * 8];
      short8 bf2 = *(const short8*)&Bsl[32 + l15][kk + quad * 8];
      short8 bf3 = *(const short8*)&Bsl[48 + l15][kk + quad * 8];
      acc[0][0] = mfma16(af0, bf0, acc[0][0]);
      acc[0][1] = mfma16(af0, bf1, acc[0][1]);
      acc[0][2] = mfma16(af0, bf2, acc[0][2]);
      acc[0][3] = mfma16(af0, bf3, acc[0][3]);
      acc[1][0] = mfma16(af1, bf0, acc[1][0]);
      acc[1][1] = mfma16(af1, bf1, acc[1][1]);
      acc[1][2] = mfma16(af1, bf2, acc[1][2]);
      acc[1][3] = mfma16(af1, bf3, acc[1][3]);
    }
  }
#pragma unroll
  for (int ms = 0; ms < 2; ++ms)
#pragma unroll
    for (int nt = 0; nt < 4; ++nt)
#pragma unroll
      for (int r = 0; r < 4; ++r) {
        int m = m0 + wave * 32 + ms * 16 + quad * 4 + r;
        if (m >= M) continue;
        int n = n0 + nt * 16 + l15;
        float x = acc[ms][nt][r] + biasQG[n];
        if (n < 256) {
          // hd^-0.5 * log2(e)  (exp2-domain attention)
          qb[(size_t)m * 256 + n] = __float2bfloat16(x * 0.25504765517f);
        } else {
          ghb[(size_t)m * 128 + (n - 256)] = __float2bfloat16(fmaxf(x, 0.f));
        }
      }
}

// ---------------------------------------------------------------------------
// 3. k|val GEMM (merged, N=512): n<256 -> kb (b,s,c); else valT (b,h,d,s).
// ---------------------------------------------------------------------------
__global__ __launch_bounds__(256) void gemm_kval(
    const bf16* __restrict__ cnb, const bf16* __restrict__ WcvcT,
    const float* __restrict__ biasCV, bf16* __restrict__ kb,
    bf16* __restrict__ valTb, int M) {
  __shared__ __align__(16) bf16 Asl[128][136];
  __shared__ __align__(16) bf16 Bsl[64][136];
  const int tid = threadIdx.x;
  const int wave = tid >> 6, lane = tid & 63, quad = lane >> 4, l15 = lane & 15;
  const int m0 = blockIdx.y * 128;
  const int n0 = blockIdx.x * 64;
  f32x4 acc[2][4];
#pragma unroll
  for (int i = 0; i < 2; ++i)
#pragma unroll
    for (int j = 0; j < 4; ++j) acc[i][j] = (f32x4){0.f, 0.f, 0.f, 0.f};

  for (int k0 = 0; k0 < 256; k0 += 128) {
    __syncthreads();
#pragma unroll
    for (int c = 0; c < 8; ++c) {
      int chunk = c * 256 + tid;
      int row = chunk >> 4, col = (chunk & 15) * 8;
      *(uint4*)&Asl[row][col] = *(const uint4*)&cnb[(size_t)(m0 + row) * 256 + k0 + col];
    }
#pragma unroll
    for (int c = 0; c < 4; ++c) {
      int chunk = c * 256 + tid;
      int row = chunk >> 4, col = (chunk & 15) * 8;
      *(uint4*)&Bsl[row][col] = *(const uint4*)&WcvcT[(size_t)(n0 + row) * 256 + k0 + col];
    }
    __syncthreads();
#pragma unroll
    for (int kk = 0; kk < 128; kk += 32) {
      short8 af0 = *(const short8*)&Asl[wave * 32 + l15][kk + quad * 8];
      short8 af1 = *(const short8*)&Asl[wave * 32 + 16 + l15][kk + quad * 8];
      short8 bf0 = *(const short8*)&Bsl[l15][kk + quad * 8];
      short8 bf1 = *(const short8*)&Bsl[16 + l15][kk + quad * 8];
      short8 bf2 = *(const short8*)&Bsl[32 + l15][kk + quad * 8];
      short8 bf3 = *(const short8*)&Bsl[48 + l15][kk + quad * 8];
      acc[0][0] = mfma16(af0, bf0, acc[0][0]);
      acc[0][1] = mfma16(af0, bf1, acc[0][1]);
      acc[0][2] = mfma16(af0, bf2, acc[0][2]);
      acc[0][3] = mfma16(af0, bf3, acc[0][3]);
      acc[1][0] = mfma16(af1, bf0, acc[1][0]);
      acc[1][1] = mfma16(af1, bf1, acc[1][1]);
      acc[1][2] = mfma16(af1, bf2, acc[1][2]);
      acc[1][3] = mfma16(af1, bf3, acc[1][3]);
    }
  }
#pragma unroll
  for (int ms = 0; ms < 2; ++ms)
#pragma unroll
    for (int nt = 0; nt < 4; ++nt)
#pragma unroll
      for (int r = 0; r < 4; ++r) {
        int m = m0 + wave * 32 + ms * 16 + quad * 4 + r;
        int n = n0 + nt * 16 + l15;
        float x = acc[ms][nt][r] + biasCV[n];
        if (n < 256) {
          kb[(size_t)m * 256 + n] = __float2bfloat16(x);
        } else {
          int n2 = n - 256;
          int bb = m >> 10, s = m & 1023;
          int hh = n2 >> 5, d = n2 & 31;
          valTb[(((size_t)(bb * NHEAD + hh) * 32 + d) << 10) + s] = __float2bfloat16(x);
        }
      }
}

// ---------------------------------------------------------------------------
// 4. attention. 128 thr (2 waves), 32 t/wave -> 64 t/block, one (b,h).
//    Grid 134x16 = 2144 blocks (8.4/CU). Single-buffer LDS (16.9 KB) +
//    register prefetch. K and V in flat fragment order (conflict-free 1KB
//    lane-contiguous reads). Coalesced ob epilogue via per-wave LDS tile.
// ---------------------------------------------------------------------------
__global__ __launch_bounds__(128) void attn_kernel(
    const bf16* __restrict__ qb, const bf16* __restrict__ kb,
    const bf16* __restrict__ valTb, const int* __restrict__ mask,
    bf16* __restrict__ ob) {
  __shared__ __align__(16) bf16 Ksl[4096];      // 8 KB
  __shared__ __align__(16) bf16 Vsl[4096];      // 8 KB
  __shared__ __align__(16) float biasl[128];    // 512 B
  const int tid = threadIdx.x;
  const int lane = tid & 63, wv = tid >> 6, quad = lane >> 4, l15 = lane & 15;
  const int b = blockIdx.y >> 3, h = blockIdx.y & 7;
  const int t0w = blockIdx.x * 64 + wv * 32;
  int tA = t0w + l15;       if (tA >= T_TOK) tA = T_TOK - 1;
  int tB = t0w + 16 + l15;  if (tB >= T_TOK) tB = T_TOK - 1;
  short8 qf0 = *(const short8*)&qb[((size_t)b * T_TOK + tA) * CDIM + h * 32 + quad * 8];
  short8 qf1 = *(const short8*)&qb[((size_t)b * T_TOK + tB) * CDIM + h * 32 + quad * 8];
  f32x4 o0a = {0.f, 0.f, 0.f, 0.f}, o1a = {0.f, 0.f, 0.f, 0.f}, o2a = {0.f, 0.f, 0.f, 0.f};
  f32x4 o0b = {0.f, 0.f, 0.f, 0.f}, o1b = {0.f, 0.f, 0.f, 0.f}, o2b = {0.f, 0.f, 0.f, 0.f};
  const short8 ones = (short8){0x3F80, 0x3F80, 0x3F80, 0x3F80,
                               0x3F80, 0x3F80, 0x3F80, 0x3F80};
  const size_t kbase = ((size_t)b * S_TOK) * CDIM + h * 32;
  const size_t vbase = (size_t)(b * NHEAD + h) << 15;
  // staging roles: 4 chunks each for K and V (128 threads, 128-s block)
  int kdst[4], vd1[4], vd2[4];
  size_t kofs[4], vofs[4];
#pragma unroll
  for (int c = 0; c < 4; ++c) {
    int idx = c * 128 + tid;
    int ks = idx >> 2, kd16 = idx & 3;              // s-row, d-group
    kdst[c] = (ks >> 4) * 512 + (ks & 15) * 32 + kd16 * 8;
    kofs[c] = (size_t)ks * CDIM + kd16 * 8;
    int vd = idx >> 4, vs8 = (idx & 15) * 8;        // d-row, s-group of 8
    int schunk = vs8 >> 5, sb = vs8 & 31;
    int kb1 = (((sb >> 2) & 3) << 3) + (((sb >> 4) & 1) << 2);
    int sb2 = sb + 4;
    int kb2 = (((sb2 >> 2) & 3) << 3) + (((sb2 >> 4) & 1) << 2);
    int base = schunk * 1024 + (vd >> 4) * 512 + (vd & 15) * 32;
    vd1[c] = base + kb1;
    vd2[c] = base + kb2;
    vofs[c] = ((size_t)vd << 10) + vs8;
  }

  uint4 kreg[4], vreg[4];
  float breg;
#pragma unroll
  for (int c = 0; c < 4; ++c) {
    kreg[c] = *(const uint4*)&kb[kbase + kofs[c]];
    vreg[c] = *(const uint4*)&valTb[vbase + vofs[c]];
  }
  breg = mask[b * S_TOK + tid] ? -12.984255368f : -1e18f;
#pragma unroll
  for (int c = 0; c < 4; ++c) {
    *(uint4*)&Ksl[kdst[c]] = kreg[c];
    uint2 lo; lo.x = vreg[c].x; lo.y = vreg[c].y;
    uint2 hi; hi.x = vreg[c].z; hi.y = vreg[c].w;
    *(uint2*)&Vsl[vd1[c]] = lo;
    *(uint2*)&Vsl[vd2[c]] = hi;
  }
  biasl[tid] = breg;
  __syncthreads();

  for (int sbi = 0; sbi < 8; ++sbi) {
    if (sbi < 7) {  // prefetch next 128-s chunk into registers
      int sb = (sbi + 1) * 128;
#pragma unroll
      for (int c = 0; c < 4; ++c) {
        kreg[c] = *(const uint4*)&kb[kbase + (size_t)sb * CDIM + kofs[c]];
        vreg[c] = *(const uint4*)&valTb[vbase + sb + vofs[c]];
      }
      breg = mask[b * S_TOK + sb + tid] ? -12.984255368f : -1e18f;
    }
#pragma unroll
    for (int ss = 0; ss < 128; ss += 32) {
      const int cb = (ss >> 5) * 1024 + l15 * 32 + quad * 8;
      short8 kf0 = *(const short8*)&Ksl[cb];
      short8 kf1 = *(const short8*)&Ksl[cb + 512];
      short8 vf0 = *(const short8*)&Vsl[cb];
      short8 vf1 = *(const short8*)&Vsl[cb + 512];
      f32x4 bias0 = *(const f32x4*)&biasl[ss + quad * 4];
      f32x4 bias1 = *(const f32x4*)&biasl[ss + 16 + quad * 4];
      // group A (t = t0w + l15)
      {
        f32x4 s0 = mfma16(kf0, qf0, bias0);
        f32x4 s1 = mfma16(kf1, qf0, bias1);
        float pa = fexp2(s0[0]), pb = fexp2(s0[1]);
        float pc = fexp2(s0[2]), pd = fexp2(s0[3]);
        float pe = fexp2(s1[0]), pf_ = fexp2(s1[1]);
        float pg = fexp2(s1[2]), ph = fexp2(s1[3]);
        uint4 pu;
        pu.x = pack_bf16(pa, pb); pu.y = pack_bf16(pc, pd);
        pu.z = pack_bf16(pe, pf_); pu.w = pack_bf16(pg, ph);
        short8 pfr = *(short8*)&pu;
        o2a = mfma16(pfr, ones, o2a);
        o0a = mfma16(pfr, vf0, o0a);
        o1a = mfma16(pfr, vf1, o1a);
      }
      // group B (t = t0w + 16 + l15)
      {
        f32x4 s0 = mfma16(kf0, qf1, bias0);
        f32x4 s1 = mfma16(kf1, qf1, bias1);
        float pa = fexp2(s0[0]), pb = fexp2(s0[1]);
        float pc = fexp2(s0[2]), pd = fexp2(s0[3]);
        float pe = fexp2(s1[0]), pf_ = fexp2(s1[1]);
        float pg = fexp2(s1[2]), ph = fexp2(s1[3]);
        uint4 pu;
        pu.x = pack_bf16(pa, pb); pu.y = pack_bf16(pc, pd);
        pu.z = pack_bf16(pe, pf_); pu.w = pack_bf16(pg, ph);
        short8 pfr = *(short8*)&pu;
        o2b = mfma16(pfr, ones, o2b);
        o0b = mfma16(pfr, vf0, o0b);
        o1b = mfma16(pfr, vf1, o1b);
      }
    }
    if (sbi < 7) {
      __syncthreads();  // all waves done reading this chunk's LDS
#pragma unroll
      for (int c = 0; c < 4; ++c) {
        *(uint4*)&Ksl[kdst[c]] = kreg[c];
        uint2 lo; lo.x = vreg[c].x; lo.y = vreg[c].y;
        uint2 hi; hi.x = vreg[c].z; hi.y = vreg[c].w;
        *(uint2*)&Vsl[vd1[c]] = lo;
        *(uint2*)&Vsl[vd2[c]] = hi;
      }
      biasl[tid] = breg;
      __syncthreads();  // writes visible
    }
  }
  // --- coalesced epilogue: per-wave [32 t][32 d] tile in Ksl ---
  bf16* tile = &Ksl[wv * 1024];
#pragma unroll
  for (int g = 0; g < 2; ++g) {
    f32x4 o0 = g ? o0b : o0a;
    f32x4 o1 = g ? o1b : o1a;
    f32x4 o2 = g ? o2b : o2a;
#pragma unroll
    for (int r = 0; r < 4; ++r) {
      float rli = 1.0f / o2[r];
      int tl = g * 16 + quad * 4 + r;
      tile[tl * 32 + l15] = __float2bfloat16(o0[r] * rli);
      tile[tl * 32 + 16 + l15] = __float2bfloat16(o1[r] * rli);
    }
  }
  // lanes: 4 lanes per t-row, each stores 16 B -> full 64 B line per row
#pragma unroll
  for (int pass = 0; pass < 2; ++pass) {
    int tl = pass * 16 + (lane >> 2);
    int d8 = (lane & 3) * 8;
    int t = t0w + tl;
    uint4 val = *(const uint4*)&tile[tl * 32 + d8];
    if (t < T_TOK)
      *(uint4*)&ob[((size_t)b * T_TOK + t) * CDIM + h * 32 + d8] = val;
  }
}

// ---------------------------------------------------------------------------
// 5. fused output: delta = o@Wo+bo, gate = tanh(gh@Wg2+bg2),
//    out = vT + gate*delta -> per-level (b,c,h,w), coalesced via LDS transpose.
// ---------------------------------------------------------------------------
__global__ __launch_bounds__(256) void gemm_out(
    const bf16* __restrict__ obuf, const bf16* __restrict__ WoT,
    const float* __restrict__ bo, const bf16* __restrict__ ghb,
    const bf16* __restrict__ Wg2T, const float* __restrict__ bg2,
    const float* __restrict__ vT, float* __restrict__ out, int M) {
  constexpr int HW[5] = {6400, 1600, 400, 100, 25};
  constexpr int TST[5] = {0, 6400, 8000, 8400, 8500};
  constexpr size_t OUTOFF[5] = {0, 3276800, 4096000, 4300800, 4352000};
  __shared__ __align__(16) char smem[52224];
  bf16 (*Asl)[136] = (bf16(*)[136])smem;             // [128][136]
  bf16 (*Bsl)[136] = (bf16(*)[136])(smem + 34816);   // [64][136]
  float (*tile)[132] = (float(*)[132])smem;          // [64][132] (aliases)
  const int tid = threadIdx.x;
  const int wave = tid >> 6, lane = tid & 63, quad = lane >> 4, l15 = lane & 15;
  const int m0 = blockIdx.y * 128, n0 = blockIdx.x * 64;
  f32x4 aD[2][4], aG[2][4];
#pragma unroll
  for (int i = 0; i < 2; ++i)
#pragma unroll
    for (int j = 0; j < 4; ++j) {
      aD[i][j] = (f32x4){0.f, 0.f, 0.f, 0.f};
      aG[i][j] = (f32x4){0.f, 0.f, 0.f, 0.f};
    }
  for (int k0 = 0; k0 < 256; k0 += 128) {
    __syncthreads();
#pragma unroll
    for (int c = 0; c < 8; ++c) {
      int chunk = c * 256 + tid;
      int row = chunk >> 4, col = (chunk & 15) * 8;
      int gr = m0 + row;
      if (gr >= M) gr = M - 1;
      *(uint4*)&Asl[row][col] = *(const uint4*)&obuf[(size_t)gr * 256 + k0 + col];
    }
#pragma unroll
    for (int c = 0; c < 4; ++c) {
      int chunk = c * 256 + tid;
      int row = chunk >> 4, col = (chunk & 15) * 8;
      *(uint4*)&Bsl[row][col] = *(const uint4*)&WoT[(size_t)(n0 + row) * 256 + k0 + col];
    }
    __syncthreads();
#pragma unroll
    for (int kk = 0; kk < 128; kk += 32) {
      short8 af0 = *(const short8*)&Asl[wave * 32 + l15][kk + quad * 8];
      short8 af1 = *(const short8*)&Asl[wave * 32 + 16 + l15][kk + quad * 8];
#pragma unroll
      for (int j = 0; j < 4; ++j) {
        short8 bfj = *(const short8*)&Bsl[j * 16 + l15][kk + quad * 8];
        aD[0][j] = mfma16(af0, bfj, aD[0][j]);
        aD[1][j] = mfma16(af1, bfj, aD[1][j]);
      }
    }
  }
  __syncthreads();
#pragma unroll
  for (int c = 0; c < 8; ++c) {
    int chunk = c * 256 + tid;
    int row = chunk >> 4, col = (chunk & 15) * 8;
    int gr = m0 + row;
    if (gr >= M) gr = M - 1;
    *(uint4*)&Asl[row][col] = *(const uint4*)&ghb[(size_t)gr * 128 + col];
  }
#pragma unroll
  for (int c = 0; c < 4; ++c) {
    int chunk = c * 256 + tid;
    int row = chunk >> 4, col = (chunk & 15) * 8;
    *(uint4*)&Bsl[row][col] = *(const uint4*)&Wg2T[(size_t)(n0 + row) * 128 + col];
  }
  __syncthreads();
#pragma unroll
  for (int kk = 0; kk < 128; kk += 32) {
    short8 af0 = *(const short8*)&Asl[wave * 32 + l15][kk + quad * 8];
    short8 af1 = *(const short8*)&Asl[wave * 32 + 16 + l15][kk + quad * 8];
#pragma unroll
    for (int j = 0; j < 4; ++j) {
      short8 bfj = *(const short8*)&Bsl[j * 16 + l15][kk + quad * 8];
      aG[0][j] = mfma16(af0, bfj, aG[0][j]);
      aG[1][j] = mfma16(af1, bfj, aG[1][j]);
    }
  }
  __syncthreads();  // Asl/Bsl done; smem becomes the transpose tile
#pragma unroll
  for (int ms = 0; ms < 2; ++ms)
#pragma unroll
    for (int nt = 0; nt < 4; ++nt) {
      int n = n0 + nt * 16 + l15;
      float bod = bo[n], bgd = bg2[n];
      float4 res;
      float tmp[4];
#pragma unroll
      for (int r = 0; r < 4; ++r) {
        float xd = aD[ms][nt][r] + bod;
        float xg = aG[ms][nt][r] + bgd;
        float xc = fminf(fmaxf(xg, -15.f), 15.f);
        float e = __expf(2.f * xc);
        float gt = (e - 1.f) / (e + 1.f);
        tmp[r] = gt * xd;
      }
      res.x = tmp[0]; res.y = tmp[1]; res.z = tmp[2]; res.w = tmp[3];
      *(float4*)&tile[nt * 16 + l15][wave * 32 + ms * 16 + quad * 4] = res;
    }
  __syncthreads();
  const int tl = tid & 127, c2 = tid >> 7;
  const int t = m0 + tl;
  const bool valid = t < M;
  int bb = (t >= T_TOK) ? 1 : 0;
  int tt = t - bb * T_TOK;
  if (tt >= T_TOK) tt = T_TOK - 1;
  int lvl = 0;
#pragma unroll
  for (int i = 1; i < 5; ++i) if (tt >= TST[i]) lvl = i;
  const int p = tt - TST[lvl], hw = HW[lvl];
  float* dst = out + OUTOFF[lvl] + ((size_t)bb * CDIM + n0) * hw + p;
  const float* vsrc = vT + ((size_t)bb * CDIM + n0) * T_TOK + tt;
#pragma unroll
  for (int c0 = 0; c0 < 32; ++c0) {
    int c = c0 * 2 + c2;
    if (valid) dst[(size_t)c * hw] = vsrc[(size_t)c * T_TOK] + tile[c][tl];
  }
}

// ---------------------------------------------------------------------------
extern "C" void kernel_launch(void* const* d_in, const int* in_sizes, int n_in,
                              void* d_out, int out_size, void* d_ws, size_t ws_size,
                              hipStream_t stream) {
  const float* q0 = (const float*)d_in[0];
  const float* q1 = (const float*)d_in[1];
  const float* q2 = (const float*)d_in[2];
  const float* q3 = (const float*)d_in[3];
  const float* q4 = (const float*)d_in[4];
  const float* cache = (const float*)d_in[5];
  const int* mask = (const int*)d_in[6];
  const float* ln_v_g = (const float*)d_in[7];
  const float* ln_v_b = (const float*)d_in[8];
  const float* ln_c_g = (const float*)d_in[9];
  const float* ln_c_b = (const float*)d_in[10];
  const float* Wv = (const float*)d_in[11];
  const float* bv = (const float*)d_in[12];
  const float* Wc = (const float*)d_in[13];
  const float* bc = (const float*)d_in[14];
  const float* Wvc = (const float*)d_in[15];
  const float* bvc = (const float*)d_in[16];
  const float* Wo = (const float*)d_in[17];
  const float* bo = (const float*)d_in[18];
  const float* Wg1 = (const float*)d_in[19];
  const float* bg1 = (const float*)d_in[20];
  const float* Wg2 = (const float*)d_in[21];
  const float* bg2 = (const float*)d_in[22];
  float* out = (float*)d_out;

  const int R = BSZ * T_TOK;              // 17050 rows
  const size_t RC = (size_t)R * CDIM;
  const size_t SC = (size_t)BSZ * S_TOK * CDIM;

  char* p = (char*)d_ws;
  float* vT = (float*)p;           p += RC * 4;
  bf16* vb = (bf16*)p;             p += RC * 2;
  bf16* vnb = (bf16*)p;            p += RC * 2;
  bf16* qb = (bf16*)p;             p += RC * 2;
  bf16* ob = (bf16*)p;             p += RC * 2;
  bf16* ghb = (bf16*)p;            p += (size_t)R * 128 * 2;
  bf16* cnb = (bf16*)p;            p += SC * 2;
  bf16* kb = (bf16*)p;             p += SC * 2;
  bf16* valTb = (bf16*)p;          p += SC * 2;
  bf16* WqgT = (bf16*)p;           p += 98304 * 2;   // [Wv(256); Wg1(128)] x 256
  bf16* WcvcT = (bf16*)p;          p += 131072 * 2;
  bf16* WoT = (bf16*)p;            p += 65536 * 2;
  bf16* Wg2T = (bf16*)p;           p += 32768 * 2;
  float* biasCV = (float*)p;       p += 512 * 4;
  float* biasQG = (float*)p;       p += 384 * 4;

  stage1<<<dim3(1661), dim3(256), 0, stream>>>(
      q0, q1, q2, q3, q4, Wv, Wc, Wvc, Wo, Wg1, Wg2, bv, bg1, bc, bvc,
      cache, ln_c_g, ln_c_b, ln_v_g, ln_v_b,
      WqgT, WcvcT, WoT, Wg2T, biasCV, biasQG, cnb, vT, vb, vnb);
  gemm_qg<<<dim3(6, 134), dim3(256), 0, stream>>>(
      vnb, vb, WqgT, biasQG, qb, ghb, R);
  gemm_kval<<<dim3(8, 16), dim3(256), 0, stream>>>(
      cnb, WcvcT, biasCV, kb, valTb, BSZ * S_TOK);
  attn_kernel<<<dim3(134, BSZ * NHEAD), dim3(128), 0, stream>>>(
      qb, kb, valTb, mask, ob);
  gemm_out<<<dim3(4, 134), dim3(256), 0, stream>>>(
      ob, WoT, bo, ghb, Wg2T, bg2, vT, out, R);
}

// Round 8
// 212.950 us; speedup vs baseline: 1.1537x; 1.1537x over previous
//
#include <hip/hip_runtime.h>
#include <hip/hip_bf16.h>
#include <math.h>

// ---------------------------------------------------------------------------
// GatedCrossAttentionBlock on MI355X (gfx950), bf16-MFMA implementation. R8.
//
// Pipeline (5 launches):
//   1. stage1   : weight transpose + bias concat + LN(cache) + build_v(+LN)
//   2. gemm_qg  : merged N=384: qb=(vn@Wv+bv)*scale*log2e | ghb=relu(v@Wg1+bg1)
//   3. gemm kval: cn@[Wc|Wvc]+bias -> kb bf16 + valTb bf16 (b,h,d,s)
//   4. attn     : R4 topology (512 thr, 8 waves, 16 t/wave, 1072 blocks =
//                 33.5 waves/CU) + flat fragment-order K/V (conflict-free),
//                 double-buffer w/ ONE barrier per sbi, register prefetch
//                 (1 K + 1 V uint4/thread), exp2-domain softmax, bias in
//                 MFMA C-op, denom via P x ones, coalesced ob epilogue.
//   5. gemm_out : dual GEMM; out = vT + tanh(gate)*delta via LDS transpose
// ---------------------------------------------------------------------------

typedef __attribute__((ext_vector_type(8))) short short8;
typedef __attribute__((ext_vector_type(4))) float f32x4;
typedef __hip_bfloat16 bf16;

#define T_TOK 8525
#define S_TOK 1024
#define CDIM  256
#define NHEAD 8
#define BSZ   2

static __device__ __forceinline__ f32x4 mfma16(short8 a, short8 b, f32x4 c) {
  return __builtin_amdgcn_mfma_f32_16x16x32_bf16(a, b, c, 0, 0, 0);
}

static __device__ __forceinline__ float fexp2(float x) {
#if __has_builtin(__builtin_amdgcn_exp2f)
  return __builtin_amdgcn_exp2f(x);
#else
  return exp2f(x);
#endif
}

static __device__ __forceinline__ unsigned int pack_bf16(float a, float b) {
#if __has_builtin(__builtin_amdgcn_perm)
  return __builtin_amdgcn_perm(__float_as_uint(b), __float_as_uint(a), 0x07060302u);
#else
  return (__float_as_uint(a) >> 16) | (__float_as_uint(b) & 0xFFFF0000u);
#endif
}

// ---------------------------------------------------------------------------
// 1. stage1: blocks 0..79 weight tiles, 80 bias concat, 81..592 LN(cache),
//            593.. build_v (+LN(v)). LDS aliased: both paths use 4160 floats.
// ---------------------------------------------------------------------------
__global__ __launch_bounds__(256) void stage1(
    const float* __restrict__ q0, const float* __restrict__ q1,
    const float* __restrict__ q2, const float* __restrict__ q3,
    const float* __restrict__ q4,
    const float* __restrict__ Wv, const float* __restrict__ Wc,
    const float* __restrict__ Wvc, const float* __restrict__ Wo,
    const float* __restrict__ Wg1, const float* __restrict__ Wg2,
    const float* __restrict__ bv, const float* __restrict__ bg1,
    const float* __restrict__ bc, const float* __restrict__ bvc,
    const float* __restrict__ cache, const float* __restrict__ ln_c_g,
    const float* __restrict__ ln_c_b, const float* __restrict__ ln_v_g,
    const float* __restrict__ ln_v_b,
    bf16* __restrict__ WqgT, bf16* __restrict__ WcvcT, bf16* __restrict__ WoT,
    bf16* __restrict__ Wg2T, float* __restrict__ biasCV,
    float* __restrict__ biasQG, bf16* __restrict__ cnb,
    float* __restrict__ vT, bf16* __restrict__ vb, bf16* __restrict__ vnb) {
  __shared__ float sm[4160];
  const int bid = blockIdx.x, tid = threadIdx.x;
  if (bid == 80) {
    biasCV[tid] = bc[tid];
    biasCV[tid + 256] = bvc[tid];
    biasQG[tid] = bv[tid];
    if (tid < 128) biasQG[256 + tid] = bg1[tid];
    return;
  }
  if (bid > 80 && bid < 593) {  // LN over cache rows
    int lane = tid & 63;
    int row = (bid - 81) * 4 + (tid >> 6);
    const float* x = cache + (size_t)row * CDIM;
    float v0 = x[lane], v1 = x[lane + 64], v2 = x[lane + 128], v3 = x[lane + 192];
    float s = v0 + v1 + v2 + v3;
    float s2 = v0 * v0 + v1 * v1 + v2 * v2 + v3 * v3;
#pragma unroll
    for (int off = 1; off < 64; off <<= 1) {
      s += __shfl_xor(s, off);
      s2 += __shfl_xor(s2, off);
    }
    float mean = s * (1.f / 256.f);
    float var = s2 * (1.f / 256.f) - mean * mean;
    float rstd = rsqrtf(var + 1e-5f);
    bf16* y = cnb + (size_t)row * CDIM;
    y[lane] = __float2bfloat16((v0 - mean) * rstd * ln_c_g[lane] + ln_c_b[lane]);
    y[lane + 64] = __float2bfloat16((v1 - mean) * rstd * ln_c_g[lane + 64] + ln_c_b[lane + 64]);
    y[lane + 128] = __float2bfloat16((v2 - mean) * rstd * ln_c_g[lane + 128] + ln_c_b[lane + 128]);
    y[lane + 192] = __float2bfloat16((v3 - mean) * rstd * ln_c_g[lane + 192] + ln_c_b[lane + 192]);
    return;
  }
  if (bid < 80) {  // weight transpose tiles
    float (*tl)[65] = (float(*)[65])sm;  // [64 n][65 k]
    const float* W; bf16* WT; int K, N, local;
    if (bid < 16)      { W = Wv;  WT = WqgT;           K = 256; N = 256; local = bid; }
    else if (bid < 32) { W = Wc;  WT = WcvcT;          K = 256; N = 256; local = bid - 16; }
    else if (bid < 48) { W = Wvc; WT = WcvcT + 65536;  K = 256; N = 256; local = bid - 32; }
    else if (bid < 64) { W = Wo;  WT = WoT;            K = 256; N = 256; local = bid - 48; }
    else if (bid < 72) { W = Wg1; WT = WqgT + 65536;   K = 256; N = 128; local = bid - 64; }
    else               { W = Wg2; WT = Wg2T;           K = 128; N = 256; local = bid - 72; }
    const int ktiles = K >> 6;
    const int K0 = (local % ktiles) * 64, N0 = (local / ktiles) * 64;
    const int kk = tid >> 4, n4 = (tid & 15) * 4;
#pragma unroll
    for (int i = 0; i < 4; ++i) {
      int k = kk + 16 * i;
      float4 w4 = *(const float4*)&W[(size_t)(K0 + k) * N + N0 + n4];
      tl[n4 + 0][k] = w4.x; tl[n4 + 1][k] = w4.y;
      tl[n4 + 2][k] = w4.z; tl[n4 + 3][k] = w4.w;
    }
    __syncthreads();
    const int nn = tid >> 4, k4 = (tid & 15) * 4;
#pragma unroll
    for (int i = 0; i < 4; ++i) {
      int n = nn + 16 * i;
      bf16 o[4] __attribute__((aligned(8)));
#pragma unroll
      for (int j = 0; j < 4; ++j) o[j] = __float2bfloat16(tl[n][k4 + j]);
      *(uint2*)&WT[(size_t)(N0 + n) * K + K0 + k4] = *(uint2*)o;
    }
    return;
  }
  // ------- build_v path -------
  constexpr int HW[5] = {6400, 1600, 400, 100, 25};
  constexpr int TST[5] = {0, 6400, 8000, 8400, 8500};
  constexpr int T16[5] = {0, 400, 500, 525, 532};
  float (*tile)[260] = (float(*)[260])sm;  // [16 p][260 c]
  const int bb = bid - 593;
  const int tileid = bb % 534, b = bb / 534;
  int lvl = 0;
#pragma unroll
  for (int i = 1; i < 5; ++i) if (tileid >= T16[i]) lvl = i;
  const int p0 = (tileid - T16[lvl]) * 16;
  const int hw = HW[lvl];
  const float* src = ((lvl == 0) ? q0 : (lvl == 1) ? q1 : (lvl == 2) ? q2
                      : (lvl == 3) ? q3 : q4) + (size_t)b * CDIM * hw;
  const int pl = tid & 15, cb = tid >> 4;
  const int pg = p0 + pl;
#pragma unroll
  for (int i = 0; i < 16; ++i) {
    int c = cb + 16 * i;
    tile[pl][c] = (pg < hw) ? src[(size_t)c * hw + pg] : 0.f;
  }
  __syncthreads();
  if (pg < hw) {
    int tglob = TST[lvl] + pg;
#pragma unroll
    for (int i = 0; i < 16; ++i) {
      int c = cb + 16 * i;
      vT[((size_t)b * CDIM + c) * T_TOK + tglob] = tile[pl][c];
    }
  }
  const int lane = tid & 63, w = tid >> 6;
#pragma unroll
  for (int rr = 0; rr < 4; ++rr) {
    int row = w * 4 + rr;
    int p = p0 + row;
    if (p >= hw) continue;
    float x0 = tile[row][lane], x1 = tile[row][lane + 64],
          x2 = tile[row][lane + 128], x3 = tile[row][lane + 192];
    float s = x0 + x1 + x2 + x3;
    float s2 = x0 * x0 + x1 * x1 + x2 * x2 + x3 * x3;
#pragma unroll
    for (int off = 1; off < 64; off <<= 1) {
      s += __shfl_xor(s, off);
      s2 += __shfl_xor(s2, off);
    }
    float mean = s * (1.f / 256.f);
    float var = s2 * (1.f / 256.f) - mean * mean;
    float rstd = rsqrtf(var + 1e-5f);
    size_t base = ((size_t)b * T_TOK + TST[lvl] + p) * CDIM;
    float xs[4] = {x0, x1, x2, x3};
#pragma unroll
    for (int j = 0; j < 4; ++j) {
      int c = lane + 64 * j;
      float x = xs[j];
      vb[base + c] = __float2bfloat16(x);
      vnb[base + c] = __float2bfloat16((x - mean) * rstd * ln_v_g[c] + ln_v_b[c]);
    }
  }
}

// ---------------------------------------------------------------------------
// 2. merged q|gh GEMM: N=384. n0<256 -> qb (A=vnb, scale); else ghb (A=vb,
//    relu). K=256. Block 128m x 64n, 4 waves.
// ---------------------------------------------------------------------------
__global__ __launch_bounds__(256) void gemm_qg(
    const bf16* __restrict__ vnb, const bf16* __restrict__ vb,
    const bf16* __restrict__ WqgT, const float* __restrict__ biasQG,
    bf16* __restrict__ qb, bf16* __restrict__ ghb, int M) {
  __shared__ __align__(16) bf16 Asl[128][136];
  __shared__ __align__(16) bf16 Bsl[64][136];
  const int tid = threadIdx.x;
  const int wave = tid >> 6, lane = tid & 63, quad = lane >> 4, l15 = lane & 15;
  const int m0 = blockIdx.y * 128;
  const int n0 = blockIdx.x * 64;
  const bf16* A = (n0 < 256) ? vnb : vb;
  f32x4 acc[2][4];
#pragma unroll
  for (int i = 0; i < 2; ++i)
#pragma unroll
    for (int j = 0; j < 4; ++j) acc[i][j] = (f32x4){0.f, 0.f, 0.f, 0.f};

  for (int k0 = 0; k0 < 256; k0 += 128) {
    __syncthreads();
#pragma unroll
    for (int c = 0; c < 8; ++c) {
      int chunk = c * 256 + tid;
      int row = chunk >> 4, col = (chunk & 15) * 8;
      int gr = m0 + row;
      if (gr >= M) gr = M - 1;
      *(uint4*)&Asl[row][col] = *(const uint4*)&A[(size_t)gr * 256 + k0 + col];
    }
#pragma unroll
    for (int c = 0; c < 4; ++c) {
      int chunk = c * 256 + tid;
      int row = chunk >> 4, col = (chunk & 15) * 8;
      *(uint4*)&Bsl[row][col] = *(const uint4*)&WqgT[(size_t)(n0 + row) * 256 + k0 + col];
    }
    __syncthreads();
#pragma unroll
    for (int kk = 0; kk < 128; kk += 32) {
      short8 af0 = *(const short8*)&Asl[wave * 32 + l15][kk + quad * 8];
      short8 af1 = *(const short8*)&Asl[wave * 32 + 16 + l15][kk + quad * 8];
      short8 bf0 = *(const short8*)&Bsl[l15][kk + quad * 8];
      short8 bf1 = *(const short8*)&Bsl[16 + l15][kk + quad * 8];
      short8 bf2 = *(const short8*)&Bsl[32 + l15][kk + quad * 8];
      short8 bf3 = *(const short8*)&Bsl[48 + l15][kk + quad * 8];
      acc[0][0] = mfma16(af0, bf0, acc[0][0]);
      acc[0][1] = mfma16(af0, bf1, acc[0][1]);
      acc[0][2] = mfma16(af0, bf2, acc[0][2]);
      acc[0][3] = mfma16(af0, bf3, acc[0][3]);
      acc[1][0] = mfma16(af1, bf0, acc[1][0]);
      acc[1][1] = mfma16(af1, bf1, acc[1][1]);
      acc[1][2] = mfma16(af1, bf2, acc[1][2]);
      acc[1][3] = mfma16(af1, bf3, acc[1][3]);
    }
  }
#pragma unroll
  for (int ms = 0; ms < 2; ++ms)
#pragma unroll
    for (int nt = 0; nt < 4; ++nt)
#pragma unroll
      for (int r = 0; r < 4; ++r) {
        int m = m0 + wave * 32 + ms * 16 + quad * 4 + r;
        if (m >= M) continue;
        int n = n0 + nt * 16 + l15;
        float x = acc[ms][nt][r] + biasQG[n];
        if (n < 256) {
          // hd^-0.5 * log2(e)  (exp2-domain attention)
          qb[(size_t)m * 256 + n] = __float2bfloat16(x * 0.25504765517f);
        } else {
          ghb[(size_t)m * 128 + (n - 256)] = __float2bfloat16(fmaxf(x, 0.f));
        }
      }
}

// ---------------------------------------------------------------------------
// 3. k|val GEMM (merged, N=512): n<256 -> kb (b,s,c); else valT (b,h,d,s).
// ---------------------------------------------------------------------------
__global__ __launch_bounds__(256) void gemm_kval(
    const bf16* __restrict__ cnb, const bf16* __restrict__ WcvcT,
    const float* __restrict__ biasCV, bf16* __restrict__ kb,
    bf16* __restrict__ valTb, int M) {
  __shared__ __align__(16) bf16 Asl[128][136];
  __shared__ __align__(16) bf16 Bsl[64][136];
  const int tid = threadIdx.x;
  const int wave = tid >> 6, lane = tid & 63, quad = lane >> 4, l15 = lane & 15;
  const int m0 = blockIdx.y * 128;
  const int n0 = blockIdx.x * 64;
  f32x4 acc[2][4];
#pragma unroll
  for (int i = 0; i < 2; ++i)
#pragma unroll
    for (int j = 0; j < 4; ++j) acc[i][j] = (f32x4){0.f, 0.f, 0.f, 0.f};

  for (int k0 = 0; k0 < 256; k0 += 128) {
    __syncthreads();
#pragma unroll
    for (int c = 0; c < 8; ++c) {
      int chunk = c * 256 + tid;
      int row = chunk >> 4, col = (chunk & 15) * 8;
      *(uint4*)&Asl[row][col] = *(const uint4*)&cnb[(size_t)(m0 + row) * 256 + k0 + col];
    }
#pragma unroll
    for (int c = 0; c < 4; ++c) {
      int chunk = c * 256 + tid;
      int row = chunk >> 4, col = (chunk & 15) * 8;
      *(uint4*)&Bsl[row][col] = *(const uint4*)&WcvcT[(size_t)(n0 + row) * 256 + k0 + col];
    }
    __syncthreads();
#pragma unroll
    for (int kk = 0; kk < 128; kk += 32) {
      short8 af0 = *(const short8*)&Asl[wave * 32 + l15][kk + quad * 8];
      short8 af1 = *(const short8*)&Asl[wave * 32 + 16 + l15][kk + quad * 8];
      short8 bf0 = *(const short8*)&Bsl[l15][kk + quad * 8];
      short8 bf1 = *(const short8*)&Bsl[16 + l15][kk + quad * 8];
      short8 bf2 = *(const short8*)&Bsl[32 + l15][kk + quad * 8];
      short8 bf3 = *(const short8*)&Bsl[48 + l15][kk + quad * 8];
      acc[0][0] = mfma16(af0, bf0, acc[0][0]);
      acc[0][1] = mfma16(af0, bf1, acc[0][1]);
      acc[0][2] = mfma16(af0, bf2, acc[0][2]);
      acc[0][3] = mfma16(af0, bf3, acc[0][3]);
      acc[1][0] = mfma16(af1, bf0, acc[1][0]);
      acc[1][1] = mfma16(af1, bf1, acc[1][1]);
      acc[1][2] = mfma16(af1, bf2, acc[1][2]);
      acc[1][3] = mfma16(af1, bf3, acc[1][3]);
    }
  }
#pragma unroll
  for (int ms = 0; ms < 2; ++ms)
#pragma unroll
    for (int nt = 0; nt < 4; ++nt)
#pragma unroll
      for (int r = 0; r < 4; ++r) {
        int m = m0 + wave * 32 + ms * 16 + quad * 4 + r;
        int n = n0 + nt * 16 + l15;
        float x = acc[ms][nt][r] + biasCV[n];
        if (n < 256) {
          kb[(size_t)m * 256 + n] = __float2bfloat16(x);
        } else {
          int n2 = n - 256;
          int bb = m >> 10, s = m & 1023;
          int hh = n2 >> 5, d = n2 & 31;
          valTb[(((size_t)(bb * NHEAD + hh) * 32 + d) << 10) + s] = __float2bfloat16(x);
        }
      }
}

// ---------------------------------------------------------------------------
// 4. attention. 512 thr (8 waves), 16 t/wave -> 128 t/block, one (b,h).
//    Grid 67x16 = 1072 blocks, 8576 waves (33.5/CU). Double-buffered flat
//    fragment-order K/V LDS (33 KB, 4 blocks/CU), ONE barrier per sbi,
//    register prefetch (1 K + 1 V uint4/thread). Conflict-free 1KB
//    lane-linear fragment reads. Coalesced ob epilogue via per-wave tile.
// ---------------------------------------------------------------------------
__global__ __launch_bounds__(512) void attn_kernel(
    const bf16* __restrict__ qb, const bf16* __restrict__ kb,
    const bf16* __restrict__ valTb, const int* __restrict__ mask,
    bf16* __restrict__ ob) {
  __shared__ __align__(16) bf16 Ksl[2][4096];   // 16 KB
  __shared__ __align__(16) bf16 Vsl[2][4096];   // 16 KB
  __shared__ __align__(16) float biasl[2][128]; // 1 KB
  const int tid = threadIdx.x;
  const int lane = tid & 63, wv = tid >> 6, quad = lane >> 4, l15 = lane & 15;
  const int b = blockIdx.y >> 3, h = blockIdx.y & 7;
  const int t0w = blockIdx.x * 128 + wv * 16;
  int tA = t0w + l15;
  if (tA >= T_TOK) tA = T_TOK - 1;
  short8 qf = *(const short8*)&qb[((size_t)b * T_TOK + tA) * CDIM + h * 32 + quad * 8];
  f32x4 o0 = {0.f, 0.f, 0.f, 0.f};
  f32x4 o1 = {0.f, 0.f, 0.f, 0.f};
  f32x4 o2 = {0.f, 0.f, 0.f, 0.f};
  const short8 ones = (short8){0x3F80, 0x3F80, 0x3F80, 0x3F80,
                               0x3F80, 0x3F80, 0x3F80, 0x3F80};
  const size_t kbase = ((size_t)b * S_TOK) * CDIM + h * 32;
  const size_t vbase = (size_t)(b * NHEAD + h) << 15;
  // staging roles: 512 threads cover one 128-s chunk with 1 K + 1 V uint4 each
  const int ks = tid >> 2, kd16 = tid & 3;          // K: s-row, d-group of 8
  const int kdst = (ks >> 4) * 512 + (ks & 15) * 32 + kd16 * 8;
  const size_t kofs = (size_t)ks * CDIM + kd16 * 8;
  const int vd = tid >> 4, vs8 = (tid & 15) * 8;    // V: d-row, s-group of 8
  const int schunk = vs8 >> 5, sb_ = vs8 & 31;
  const int kb1 = (((sb_ >> 2) & 3) << 3) + (((sb_ >> 4) & 1) << 2);
  const int sb2_ = sb_ + 4;
  const int kb2 = (((sb2_ >> 2) & 3) << 3) + (((sb2_ >> 4) & 1) << 2);
  const int vbl = schunk * 1024 + (vd >> 4) * 512 + (vd & 15) * 32;
  const int vd1 = vbl + kb1, vd2 = vbl + kb2;
  const size_t vofs = ((size_t)vd << 10) + vs8;

  uint4 kreg = *(const uint4*)&kb[kbase + kofs];
  uint4 vreg = *(const uint4*)&valTb[vbase + vofs];
  float breg = 0.f;
  if (tid < 128) breg = mask[b * S_TOK + tid] ? -12.984255368f : -1e18f;
  *(uint4*)&Ksl[0][kdst] = kreg;
  {
    uint2 lo; lo.x = vreg.x; lo.y = vreg.y;
    uint2 hi; hi.x = vreg.z; hi.y = vreg.w;
    *(uint2*)&Vsl[0][vd1] = lo;
    *(uint2*)&Vsl[0][vd2] = hi;
  }
  if (tid < 128) biasl[0][tid] = breg;
  __syncthreads();

  for (int sbi = 0; sbi < 8; ++sbi) {
    const int cur = sbi & 1;
    if (sbi < 7) {  // prefetch next 128-s chunk into registers
      int sb = (sbi + 1) * 128;
      kreg = *(const uint4*)&kb[kbase + (size_t)sb * CDIM + kofs];
      vreg = *(const uint4*)&valTb[vbase + sb + vofs];
      if (tid < 128) breg = mask[b * S_TOK + sb + tid] ? -12.984255368f : -1e18f;
    }
#pragma unroll
    for (int ss = 0; ss < 128; ss += 32) {
      const int cb = (ss >> 5) * 1024 + l15 * 32 + quad * 8;
      short8 kf0 = *(const short8*)&Ksl[cur][cb];
      short8 kf1 = *(const short8*)&Ksl[cur][cb + 512];
      short8 vf0 = *(const short8*)&Vsl[cur][cb];
      short8 vf1 = *(const short8*)&Vsl[cur][cb + 512];
      f32x4 bias0 = *(const f32x4*)&biasl[cur][ss + quad * 4];
      f32x4 bias1 = *(const f32x4*)&biasl[cur][ss + 16 + quad * 4];
      f32x4 s0 = mfma16(kf0, qf, bias0);
      f32x4 s1 = mfma16(kf1, qf, bias1);
      float pa = fexp2(s0[0]), pb = fexp2(s0[1]);
      float pc = fexp2(s0[2]), pd = fexp2(s0[3]);
      float pe = fexp2(s1[0]), pf_ = fexp2(s1[1]);
      float pg = fexp2(s1[2]), ph = fexp2(s1[3]);
      uint4 pu;
      pu.x = pack_bf16(pa, pb); pu.y = pack_bf16(pc, pd);
      pu.z = pack_bf16(pe, pf_); pu.w = pack_bf16(pg, ph);
      short8 pfr = *(short8*)&pu;
      o2 = mfma16(pfr, ones, o2);
      o0 = mfma16(pfr, vf0, o0);
      o1 = mfma16(pfr, vf1, o1);
    }
    if (sbi < 7) {
      // write the OTHER buffer: its readers finished before the previous
      // barrier, so no pre-write barrier needed. One barrier per sbi.
      const int nxt = cur ^ 1;
      *(uint4*)&Ksl[nxt][kdst] = kreg;
      uint2 lo; lo.x = vreg.x; lo.y = vreg.y;
      uint2 hi; hi.x = vreg.z; hi.y = vreg.w;
      *(uint2*)&Vsl[nxt][vd1] = lo;
      *(uint2*)&Vsl[nxt][vd2] = hi;
      if (tid < 128) biasl[nxt][tid] = breg;
    }
    __syncthreads();
  }
  // --- coalesced epilogue: per-wave [16 t][32 d] tile in Ksl ---
  bf16* tile = &Ksl[0][0] + wv * 512;
#pragma unroll
  for (int r = 0; r < 4; ++r) {
    float rli = 1.0f / o2[r];
    int tl = quad * 4 + r;
    tile[tl * 32 + l15] = __float2bfloat16(o0[r] * rli);
    tile[tl * 32 + 16 + l15] = __float2bfloat16(o1[r] * rli);
  }
  // 4 lanes per t-row x 16 B = full 64 B line per (t, h)-slice
  {
    int tl = lane >> 2;
    int d8 = (lane & 3) * 8;
    int t = t0w + tl;
    uint4 val = *(const uint4*)&tile[tl * 32 + d8];
    if (t < T_TOK)
      *(uint4*)&ob[((size_t)b * T_TOK + t) * CDIM + h * 32 + d8] = val;
  }
}

// ---------------------------------------------------------------------------
// 5. fused output: delta = o@Wo+bo, gate = tanh(gh@Wg2+bg2),
//    out = vT + gate*delta -> per-level (b,c,h,w), coalesced via LDS transpose.
// ---------------------------------------------------------------------------
__global__ __launch_bounds__(256) void gemm_out(
    const bf16* __restrict__ obuf, const bf16* __restrict__ WoT,
    const float* __restrict__ bo, const bf16* __restrict__ ghb,
    const bf16* __restrict__ Wg2T, const float* __restrict__ bg2,
    const float* __restrict__ vT, float* __restrict__ out, int M) {
  constexpr int HW[5] = {6400, 1600, 400, 100, 25};
  constexpr int TST[5] = {0, 6400, 8000, 8400, 8500};
  constexpr size_t OUTOFF[5] = {0, 3276800, 4096000, 4300800, 4352000};
  __shared__ __align__(16) char smem[52224];
  bf16 (*Asl)[136] = (bf16(*)[136])smem;             // [128][136]
  bf16 (*Bsl)[136] = (bf16(*)[136])(smem + 34816);   // [64][136]
  float (*tile)[132] = (float(*)[132])smem;          // [64][132] (aliases)
  const int tid = threadIdx.x;
  const int wave = tid >> 6, lane = tid & 63, quad = lane >> 4, l15 = lane & 15;
  const int m0 = blockIdx.y * 128, n0 = blockIdx.x * 64;
  f32x4 aD[2][4], aG[2][4];
#pragma unroll
  for (int i = 0; i < 2; ++i)
#pragma unroll
    for (int j = 0; j < 4; ++j) {
      aD[i][j] = (f32x4){0.f, 0.f, 0.f, 0.f};
      aG[i][j] = (f32x4){0.f, 0.f, 0.f, 0.f};
    }
  for (int k0 = 0; k0 < 256; k0 += 128) {
    __syncthreads();
#pragma unroll
    for (int c = 0; c < 8; ++c) {
      int chunk = c * 256 + tid;
      int row = chunk >> 4, col = (chunk & 15) * 8;
      int gr = m0 + row;
      if (gr >= M) gr = M - 1;
      *(uint4*)&Asl[row][col] = *(const uint4*)&obuf[(size_t)gr * 256 + k0 + col];
    }
#pragma unroll
    for (int c = 0; c < 4; ++c) {
      int chunk = c * 256 + tid;
      int row = chunk >> 4, col = (chunk & 15) * 8;
      *(uint4*)&Bsl[row][col] = *(const uint4*)&WoT[(size_t)(n0 + row) * 256 + k0 + col];
    }
    __syncthreads();
#pragma unroll
    for (int kk = 0; kk < 128; kk += 32) {
      short8 af0 = *(const short8*)&Asl[wave * 32 + l15][kk + quad * 8];
      short8 af1 = *(const short8*)&Asl[wave * 32 + 16 + l15][kk + quad * 8];
#pragma unroll
      for (int j = 0; j < 4; ++j) {
        short8 bfj = *(const short8*)&Bsl[j * 16 + l15][kk + quad * 8];
        aD[0][j] = mfma16(af0, bfj, aD[0][j]);
        aD[1][j] = mfma16(af1, bfj, aD[1][j]);
      }
    }
  }
  __syncthreads();
#pragma unroll
  for (int c = 0; c < 8; ++c) {
    int chunk = c * 256 + tid;
    int row = chunk >> 4, col = (chunk & 15) * 8;
    int gr = m0 + row;
    if (gr >= M) gr = M - 1;
    *(uint4*)&Asl[row][col] = *(const uint4*)&ghb[(size_t)gr * 128 + col];
  }
#pragma unroll
  for (int c = 0; c < 4; ++c) {
    int chunk = c * 256 + tid;
    int row = chunk >> 4, col = (chunk & 15) * 8;
    *(uint4*)&Bsl[row][col] = *(const uint4*)&Wg2T[(size_t)(n0 + row) * 128 + col];
  }
  __syncthreads();
#pragma unroll
  for (int kk = 0; kk < 128; kk += 32) {
    short8 af0 = *(const short8*)&Asl[wave * 32 + l15][kk + quad * 8];
    short8 af1 = *(const short8*)&Asl[wave * 32 + 16 + l15][kk + quad * 8];
#pragma unroll
    for (int j = 0; j < 4; ++j) {
      short8 bfj = *(const short8*)&Bsl[j * 16 + l15][kk + quad * 8];
      aG[0][j] = mfma16(af0, bfj, aG[0][j]);
      aG[1][j] = mfma16(af1, bfj, aG[1][j]);
    }
  }
  __syncthreads();  // Asl/Bsl done; smem becomes the transpose tile
#pragma unroll
  for (int ms = 0; ms < 2; ++ms)
#pragma unroll
    for (int nt = 0; nt < 4; ++nt) {
      int n = n0 + nt * 16 + l15;
      float bod = bo[n], bgd = bg2[n];
      float4 res;
      float tmp[4];
#pragma unroll
      for (int r = 0; r < 4; ++r) {
        float xd = aD[ms][nt][r] + bod;
        float xg = aG[ms][nt][r] + bgd;
        float xc = fminf(fmaxf(xg, -15.f), 15.f);
        float e = __expf(2.f * xc);
        float gt = (e - 1.f) / (e + 1.f);
        tmp[r] = gt * xd;
      }
      res.x = tmp[0]; res.y = tmp[1]; res.z = tmp[2]; res.w = tmp[3];
      *(float4*)&tile[nt * 16 + l15][wave * 32 + ms * 16 + quad * 4] = res;
    }
  __syncthreads();
  const int tl = tid & 127, c2 = tid >> 7;
  const int t = m0 + tl;
  const bool valid = t < M;
  int bb = (t >= T_TOK) ? 1 : 0;
  int tt = t - bb * T_TOK;
  if (tt >= T_TOK) tt = T_TOK - 1;
  int lvl = 0;
#pragma unroll
  for (int i = 1; i < 5; ++i) if (tt >= TST[i]) lvl = i;
  const int p = tt - TST[lvl], hw = HW[lvl];
  float* dst = out + OUTOFF[lvl] + ((size_t)bb * CDIM + n0) * hw + p;
  const float* vsrc = vT + ((size_t)bb * CDIM + n0) * T_TOK + tt;
#pragma unroll
  for (int c0 = 0; c0 < 32; ++c0) {
    int c = c0 * 2 + c2;
    if (valid) dst[(size_t)c * hw] = vsrc[(size_t)c * T_TOK] + tile[c][tl];
  }
}

// ---------------------------------------------------------------------------
extern "C" void kernel_launch(void* const* d_in, const int* in_sizes, int n_in,
                              void* d_out, int out_size, void* d_ws, size_t ws_size,
                              hipStream_t stream) {
  const float* q0 = (const float*)d_in[0];
  const float* q1 = (const float*)d_in[1];
  const float* q2 = (const float*)d_in[2];
  const float* q3 = (const float*)d_in[3];
  const float* q4 = (const float*)d_in[4];
  const float* cache = (const float*)d_in[5];
  const int* mask = (const int*)d_in[6];
  const float* ln_v_g = (const float*)d_in[7];
  const float* ln_v_b = (const float*)d_in[8];
  const float* ln_c_g = (const float*)d_in[9];
  const float* ln_c_b = (const float*)d_in[10];
  const float* Wv = (const float*)d_in[11];
  const float* bv = (const float*)d_in[12];
  const float* Wc = (const float*)d_in[13];
  const float* bc = (const float*)d_in[14];
  const float* Wvc = (const float*)d_in[15];
  const float* bvc = (const float*)d_in[16];
  const float* Wo = (const float*)d_in[17];
  const float* bo = (const float*)d_in[18];
  const float* Wg1 = (const float*)d_in[19];
  const float* bg1 = (const float*)d_in[20];
  const float* Wg2 = (const float*)d_in[21];
  const float* bg2 = (const float*)d_in[22];
  float* out = (float*)d_out;

  const int R = BSZ * T_TOK;              // 17050 rows
  const size_t RC = (size_t)R * CDIM;
  const size_t SC = (size_t)BSZ * S_TOK * CDIM;

  char* p = (char*)d_ws;
  float* vT = (float*)p;           p += RC * 4;
  bf16* vb = (bf16*)p;             p += RC * 2;
  bf16* vnb = (bf16*)p;            p += RC * 2;
  bf16* qb = (bf16*)p;             p += RC * 2;
  bf16* ob = (bf16*)p;             p += RC * 2;
  bf16* ghb = (bf16*)p;            p += (size_t)R * 128 * 2;
  bf16* cnb = (bf16*)p;            p += SC * 2;
  bf16* kb = (bf16*)p;             p += SC * 2;
  bf16* valTb = (bf16*)p;          p += SC * 2;
  bf16* WqgT = (bf16*)p;           p += 98304 * 2;   // [Wv(256); Wg1(128)] x 256
  bf16* WcvcT = (bf16*)p;          p += 131072 * 2;
  bf16* WoT = (bf16*)p;            p += 65536 * 2;
  bf16* Wg2T = (bf16*)p;           p += 32768 * 2;
  float* biasCV = (float*)p;       p += 512 * 4;
  float* biasQG = (float*)p;       p += 384 * 4;

  stage1<<<dim3(1661), dim3(256), 0, stream>>>(
      q0, q1, q2, q3, q4, Wv, Wc, Wvc, Wo, Wg1, Wg2, bv, bg1, bc, bvc,
      cache, ln_c_g, ln_c_b, ln_v_g, ln_v_b,
      WqgT, WcvcT, WoT, Wg2T, biasCV, biasQG, cnb, vT, vb, vnb);
  gemm_qg<<<dim3(6, 134), dim3(256), 0, stream>>>(
      vnb, vb, WqgT, biasQG, qb, ghb, R);
  gemm_kval<<<dim3(8, 16), dim3(256), 0, stream>>>(
      cnb, WcvcT, biasCV, kb, valTb, BSZ * S_TOK);
  attn_kernel<<<dim3(67, BSZ * NHEAD), dim3(512), 0, stream>>>(
      qb, kb, valTb, mask, ob);
  gemm_out<<<dim3(4, 134), dim3(256), 0, stream>>>(
      ob, WoT, bo, ghb, Wg2T, bg2, vT, out, R);
}

// Round 9
// 205.868 us; speedup vs baseline: 1.1934x; 1.0344x over previous
//
#include <hip/hip_runtime.h>
#include <hip/hip_bf16.h>
#include <math.h>

// ---------------------------------------------------------------------------
// GatedCrossAttentionBlock on MI355X (gfx950), bf16-MFMA implementation. R9.
//
// Pipeline (4 launches):
//   1. stage1    : weight transpose + bias concat + packed-mask build +
//                  LN(cache) + build_v(+LN); residual kept as vTb bf16 c-major
//   2. gemm_fused: [blocks 0..803]  qb=(vn@Wv+bv)*scale*log2e | ghb=relu(v@Wg1+bg1)
//                  [blocks 804..931] kb|valT = cn@[Wc|Wvc]+bias
//   3. attn      : R8 topology (512 thr, 8 waves, 16 t/wave, dbuf LDS, one
//                  barrier/sbi) + AND-mask softmax (no bias reads: p =
//                  exp2(score) & mask16 — shift cancels), denom via P x ones,
//                  flat fragment-order K/V, coalesced ob epilogue.
//   4. gemm_out  : dual GEMM; out = bf16(v) + tanh(gate)*delta, LDS transpose
// ---------------------------------------------------------------------------

typedef __attribute__((ext_vector_type(8))) short short8;
typedef __attribute__((ext_vector_type(4))) float f32x4;
typedef __hip_bfloat16 bf16;

#define T_TOK 8525
#define S_TOK 1024
#define CDIM  256
#define NHEAD 8
#define BSZ   2

static __device__ __forceinline__ f32x4 mfma16(short8 a, short8 b, f32x4 c) {
  return __builtin_amdgcn_mfma_f32_16x16x32_bf16(a, b, c, 0, 0, 0);
}

static __device__ __forceinline__ float fexp2(float x) {
#if __has_builtin(__builtin_amdgcn_exp2f)
  return __builtin_amdgcn_exp2f(x);
#else
  return exp2f(x);
#endif
}

static __device__ __forceinline__ unsigned int pack_bf16(float a, float b) {
#if __has_builtin(__builtin_amdgcn_perm)
  return __builtin_amdgcn_perm(__float_as_uint(b), __float_as_uint(a), 0x07060302u);
#else
  return (__float_as_uint(a) >> 16) | (__float_as_uint(b) & 0xFFFF0000u);
#endif
}

// ---------------------------------------------------------------------------
// 1. stage1: blocks 0..79 weight tiles, 80 bias concat + packed mask,
//            81..592 LN(cache), 593.. build_v (+LN(v)).
// ---------------------------------------------------------------------------
__global__ __launch_bounds__(256) void stage1(
    const float* __restrict__ q0, const float* __restrict__ q1,
    const float* __restrict__ q2, const float* __restrict__ q3,
    const float* __restrict__ q4,
    const float* __restrict__ Wv, const float* __restrict__ Wc,
    const float* __restrict__ Wvc, const float* __restrict__ Wo,
    const float* __restrict__ Wg1, const float* __restrict__ Wg2,
    const float* __restrict__ bv, const float* __restrict__ bg1,
    const float* __restrict__ bc, const float* __restrict__ bvc,
    const float* __restrict__ cache, const int* __restrict__ mask,
    const float* __restrict__ ln_c_g, const float* __restrict__ ln_c_b,
    const float* __restrict__ ln_v_g, const float* __restrict__ ln_v_b,
    bf16* __restrict__ WqgT, bf16* __restrict__ WcvcT, bf16* __restrict__ WoT,
    bf16* __restrict__ Wg2T, float* __restrict__ biasCV,
    float* __restrict__ biasQG, unsigned int* __restrict__ mpk,
    bf16* __restrict__ cnb, bf16* __restrict__ vTb,
    bf16* __restrict__ vb, bf16* __restrict__ vnb) {
  __shared__ float sm[4160];
  const int bid = blockIdx.x, tid = threadIdx.x;
  if (bid == 80) {
    biasCV[tid] = bc[tid];
    biasCV[tid + 256] = bvc[tid];
    biasQG[tid] = bv[tid];
    if (tid < 128) biasQG[256 + tid] = bg1[tid];
    // packed 16-bit masks: mpk[b*512 + j] covers s = 2j, 2j+1
#pragma unroll
    for (int j = tid; j < 1024; j += 256) {
      int bb = j >> 9, s2 = (j & 511) * 2;
      mpk[j] = (mask[bb * 1024 + s2] ? 0xFFFFu : 0u) |
               (mask[bb * 1024 + s2 + 1] ? 0xFFFF0000u : 0u);
    }
    return;
  }
  if (bid > 80 && bid < 593) {  // LN over cache rows
    int lane = tid & 63;
    int row = (bid - 81) * 4 + (tid >> 6);
    const float* x = cache + (size_t)row * CDIM;
    float v0 = x[lane], v1 = x[lane + 64], v2 = x[lane + 128], v3 = x[lane + 192];
    float s = v0 + v1 + v2 + v3;
    float s2 = v0 * v0 + v1 * v1 + v2 * v2 + v3 * v3;
#pragma unroll
    for (int off = 1; off < 64; off <<= 1) {
      s += __shfl_xor(s, off);
      s2 += __shfl_xor(s2, off);
    }
    float mean = s * (1.f / 256.f);
    float var = s2 * (1.f / 256.f) - mean * mean;
    float rstd = rsqrtf(var + 1e-5f);
    bf16* y = cnb + (size_t)row * CDIM;
    y[lane] = __float2bfloat16((v0 - mean) * rstd * ln_c_g[lane] + ln_c_b[lane]);
    y[lane + 64] = __float2bfloat16((v1 - mean) * rstd * ln_c_g[lane + 64] + ln_c_b[lane + 64]);
    y[lane + 128] = __float2bfloat16((v2 - mean) * rstd * ln_c_g[lane + 128] + ln_c_b[lane + 128]);
    y[lane + 192] = __float2bfloat16((v3 - mean) * rstd * ln_c_g[lane + 192] + ln_c_b[lane + 192]);
    return;
  }
  if (bid < 80) {  // weight transpose tiles
    float (*tl)[65] = (float(*)[65])sm;  // [64 n][65 k]
    const float* W; bf16* WT; int K, N, local;
    if (bid < 16)      { W = Wv;  WT = WqgT;           K = 256; N = 256; local = bid; }
    else if (bid < 32) { W = Wc;  WT = WcvcT;          K = 256; N = 256; local = bid - 16; }
    else if (bid < 48) { W = Wvc; WT = WcvcT + 65536;  K = 256; N = 256; local = bid - 32; }
    else if (bid < 64) { W = Wo;  WT = WoT;            K = 256; N = 256; local = bid - 48; }
    else if (bid < 72) { W = Wg1; WT = WqgT + 65536;   K = 256; N = 128; local = bid - 64; }
    else               { W = Wg2; WT = Wg2T;           K = 128; N = 256; local = bid - 72; }
    const int ktiles = K >> 6;
    const int K0 = (local % ktiles) * 64, N0 = (local / ktiles) * 64;
    const int kk = tid >> 4, n4 = (tid & 15) * 4;
#pragma unroll
    for (int i = 0; i < 4; ++i) {
      int k = kk + 16 * i;
      float4 w4 = *(const float4*)&W[(size_t)(K0 + k) * N + N0 + n4];
      tl[n4 + 0][k] = w4.x; tl[n4 + 1][k] = w4.y;
      tl[n4 + 2][k] = w4.z; tl[n4 + 3][k] = w4.w;
    }
    __syncthreads();
    const int nn = tid >> 4, k4 = (tid & 15) * 4;
#pragma unroll
    for (int i = 0; i < 4; ++i) {
      int n = nn + 16 * i;
      bf16 o[4] __attribute__((aligned(8)));
#pragma unroll
      for (int j = 0; j < 4; ++j) o[j] = __float2bfloat16(tl[n][k4 + j]);
      *(uint2*)&WT[(size_t)(N0 + n) * K + K0 + k4] = *(uint2*)o;
    }
    return;
  }
  // ------- build_v path -------
  constexpr int HW[5] = {6400, 1600, 400, 100, 25};
  constexpr int TST[5] = {0, 6400, 8000, 8400, 8500};
  constexpr int T16[5] = {0, 400, 500, 525, 532};
  float (*tile)[260] = (float(*)[260])sm;  // [16 p][260 c]
  const int bb = bid - 593;
  const int tileid = bb % 534, b = bb / 534;
  int lvl = 0;
#pragma unroll
  for (int i = 1; i < 5; ++i) if (tileid >= T16[i]) lvl = i;
  const int p0 = (tileid - T16[lvl]) * 16;
  const int hw = HW[lvl];
  const float* src = ((lvl == 0) ? q0 : (lvl == 1) ? q1 : (lvl == 2) ? q2
                      : (lvl == 3) ? q3 : q4) + (size_t)b * CDIM * hw;
  const int pl = tid & 15, cb = tid >> 4;
  const int pg = p0 + pl;
#pragma unroll
  for (int i = 0; i < 16; ++i) {
    int c = cb + 16 * i;
    tile[pl][c] = (pg < hw) ? src[(size_t)c * hw + pg] : 0.f;
  }
  __syncthreads();
  if (pg < hw) {
    int tglob = TST[lvl] + pg;
#pragma unroll
    for (int i = 0; i < 16; ++i) {
      int c = cb + 16 * i;
      vTb[((size_t)b * CDIM + c) * T_TOK + tglob] = __float2bfloat16(tile[pl][c]);
    }
  }
  const int lane = tid & 63, w = tid >> 6;
#pragma unroll
  for (int rr = 0; rr < 4; ++rr) {
    int row = w * 4 + rr;
    int p = p0 + row;
    if (p >= hw) continue;
    float x0 = tile[row][lane], x1 = tile[row][lane + 64],
          x2 = tile[row][lane + 128], x3 = tile[row][lane + 192];
    float s = x0 + x1 + x2 + x3;
    float s2 = x0 * x0 + x1 * x1 + x2 * x2 + x3 * x3;
#pragma unroll
    for (int off = 1; off < 64; off <<= 1) {
      s += __shfl_xor(s, off);
      s2 += __shfl_xor(s2, off);
    }
    float mean = s * (1.f / 256.f);
    float var = s2 * (1.f / 256.f) - mean * mean;
    float rstd = rsqrtf(var + 1e-5f);
    size_t base = ((size_t)b * T_TOK + TST[lvl] + p) * CDIM;
    float xs[4] = {x0, x1, x2, x3};
#pragma unroll
    for (int j = 0; j < 4; ++j) {
      int c = lane + 64 * j;
      float x = xs[j];
      vb[base + c] = __float2bfloat16(x);
      vnb[base + c] = __float2bfloat16((x - mean) * rstd * ln_v_g[c] + ln_v_b[c]);
    }
  }
}

// ---------------------------------------------------------------------------
// 2. fused GEMM: blocks 0..803 = q|gh (M=17050, N=384), 804..931 = k|val
//    (M=2048, N=512). Block 128m x 64n, 4 waves, K=256.
// ---------------------------------------------------------------------------
__global__ __launch_bounds__(256) void gemm_fused(
    const bf16* __restrict__ vnb, const bf16* __restrict__ vb,
    const bf16* __restrict__ WqgT, const float* __restrict__ biasQG,
    bf16* __restrict__ qb, bf16* __restrict__ ghb,
    const bf16* __restrict__ cnb, const bf16* __restrict__ WcvcT,
    const float* __restrict__ biasCV, bf16* __restrict__ kb,
    bf16* __restrict__ valTb) {
  __shared__ __align__(16) bf16 Asl[128][136];
  __shared__ __align__(16) bf16 Bsl[64][136];
  const int tid = threadIdx.x;
  const int wave = tid >> 6, lane = tid & 63, quad = lane >> 4, l15 = lane & 15;
  const int bid = blockIdx.x;
  const bool kval = bid >= 804;
  int m0, n0, M;
  const bf16 *A, *BW;
  const float* bias;
  if (!kval) {
    m0 = (bid / 6) * 128; n0 = (bid % 6) * 64;
    A = (n0 < 256) ? vnb : vb; BW = WqgT; bias = biasQG; M = BSZ * T_TOK;
  } else {
    int i = bid - 804;
    m0 = (i / 8) * 128; n0 = (i % 8) * 64;
    A = cnb; BW = WcvcT; bias = biasCV; M = BSZ * S_TOK;
  }
  f32x4 acc[2][4];
#pragma unroll
  for (int i = 0; i < 2; ++i)
#pragma unroll
    for (int j = 0; j < 4; ++j) acc[i][j] = (f32x4){0.f, 0.f, 0.f, 0.f};

  for (int k0 = 0; k0 < 256; k0 += 128) {
    __syncthreads();
#pragma unroll
    for (int c = 0; c < 8; ++c) {
      int chunk = c * 256 + tid;
      int row = chunk >> 4, col = (chunk & 15) * 8;
      int gr = m0 + row;
      if (gr >= M) gr = M - 1;
      *(uint4*)&Asl[row][col] = *(const uint4*)&A[(size_t)gr * 256 + k0 + col];
    }
#pragma unroll
    for (int c = 0; c < 4; ++c) {
      int chunk = c * 256 + tid;
      int row = chunk >> 4, col = (chunk & 15) * 8;
      *(uint4*)&Bsl[row][col] = *(const uint4*)&BW[(size_t)(n0 + row) * 256 + k0 + col];
    }
    __syncthreads();
#pragma unroll
    for (int kk = 0; kk < 128; kk += 32) {
      short8 af0 = *(const short8*)&Asl[wave * 32 + l15][kk + quad * 8];
      short8 af1 = *(const short8*)&Asl[wave * 32 + 16 + l15][kk + quad * 8];
      short8 bf0 = *(const short8*)&Bsl[l15][kk + quad * 8];
      short8 bf1 = *(const short8*)&Bsl[16 + l15][kk + quad * 8];
      short8 bf2 = *(const short8*)&Bsl[32 + l15][kk + quad * 8];
      short8 bf3 = *(const short8*)&Bsl[48 + l15][kk + quad * 8];
      acc[0][0] = mfma16(af0, bf0, acc[0][0]);
      acc[0][1] = mfma16(af0, bf1, acc[0][1]);
      acc[0][2] = mfma16(af0, bf2, acc[0][2]);
      acc[0][3] = mfma16(af0, bf3, acc[0][3]);
      acc[1][0] = mfma16(af1, bf0, acc[1][0]);
      acc[1][1] = mfma16(af1, bf1, acc[1][1]);
      acc[1][2] = mfma16(af1, bf2, acc[1][2]);
      acc[1][3] = mfma16(af1, bf3, acc[1][3]);
    }
  }
#pragma unroll
  for (int ms = 0; ms < 2; ++ms)
#pragma unroll
    for (int nt = 0; nt < 4; ++nt)
#pragma unroll
      for (int r = 0; r < 4; ++r) {
        int m = m0 + wave * 32 + ms * 16 + quad * 4 + r;
        if (m >= M) continue;
        int n = n0 + nt * 16 + l15;
        float x = acc[ms][nt][r] + bias[n];
        if (!kval) {
          if (n < 256) {
            // hd^-0.5 * log2(e)  (exp2-domain attention)
            qb[(size_t)m * 256 + n] = __float2bfloat16(x * 0.25504765517f);
          } else {
            ghb[(size_t)m * 128 + (n - 256)] = __float2bfloat16(fmaxf(x, 0.f));
          }
        } else {
          if (n < 256) {
            kb[(size_t)m * 256 + n] = __float2bfloat16(x);
          } else {
            int n2 = n - 256;
            int bb = m >> 10, s = m & 1023;
            int hh = n2 >> 5, d = n2 & 31;
            valTb[(((size_t)(bb * NHEAD + hh) * 32 + d) << 10) + s] = __float2bfloat16(x);
          }
        }
      }
}

// ---------------------------------------------------------------------------
// 3. attention. 512 thr (8 waves), 16 t/wave -> 128 t/block, one (b,h).
//    Grid 67x16 = 1072 blocks (33.5 waves/CU). Double-buffered flat
//    fragment-order K/V (32.5 KB), one barrier per sbi, register prefetch.
//    AND-mask softmax: p = exp2(score) & mask16 (packed masks from L1),
//    denominator via P x ones MFMA. Coalesced ob epilogue.
// ---------------------------------------------------------------------------
__global__ __launch_bounds__(512) void attn_kernel(
    const bf16* __restrict__ qb, const bf16* __restrict__ kb,
    const bf16* __restrict__ valTb, const unsigned int* __restrict__ mpk,
    bf16* __restrict__ ob) {
  __shared__ __align__(16) bf16 Ksl[2][4096];   // 16 KB
  __shared__ __align__(16) bf16 Vsl[2][4096];   // 16 KB
  const int tid = threadIdx.x;
  const int lane = tid & 63, wv = tid >> 6, quad = lane >> 4, l15 = lane & 15;
  const int b = blockIdx.y >> 3, h = blockIdx.y & 7;
  const int t0w = blockIdx.x * 128 + wv * 16;
  int tA = t0w + l15;
  if (tA >= T_TOK) tA = T_TOK - 1;
  short8 qf = *(const short8*)&qb[((size_t)b * T_TOK + tA) * CDIM + h * 32 + quad * 8];
  f32x4 o0 = {0.f, 0.f, 0.f, 0.f};
  f32x4 o1 = {0.f, 0.f, 0.f, 0.f};
  f32x4 o2 = {0.f, 0.f, 0.f, 0.f};
  const f32x4 zero4 = {0.f, 0.f, 0.f, 0.f};
  const short8 ones = (short8){0x3F80, 0x3F80, 0x3F80, 0x3F80,
                               0x3F80, 0x3F80, 0x3F80, 0x3F80};
  const size_t kbase = ((size_t)b * S_TOK) * CDIM + h * 32;
  const size_t vbase = (size_t)(b * NHEAD + h) << 15;
  const unsigned int* mrow = mpk + b * 512;
  // staging roles: 512 threads cover one 128-s chunk with 1 K + 1 V uint4 each
  const int ks = tid >> 2, kd16 = tid & 3;          // K: s-row, d-group of 8
  const int kdst = (ks >> 4) * 512 + (ks & 15) * 32 + kd16 * 8;
  const size_t kofs = (size_t)ks * CDIM + kd16 * 8;
  const int vd = tid >> 4, vs8 = (tid & 15) * 8;    // V: d-row, s-group of 8
  const int schunk = vs8 >> 5, sb_ = vs8 & 31;
  const int kb1 = (((sb_ >> 2) & 3) << 3) + (((sb_ >> 4) & 1) << 2);
  const int sb2_ = sb_ + 4;
  const int kb2 = (((sb2_ >> 2) & 3) << 3) + (((sb2_ >> 4) & 1) << 2);
  const int vbl = schunk * 1024 + (vd >> 4) * 512 + (vd & 15) * 32;
  const int vd1 = vbl + kb1, vd2 = vbl + kb2;
  const size_t vofs = ((size_t)vd << 10) + vs8;

  uint4 kreg = *(const uint4*)&kb[kbase + kofs];
  uint4 vreg = *(const uint4*)&valTb[vbase + vofs];
  *(uint4*)&Ksl[0][kdst] = kreg;
  {
    uint2 lo; lo.x = vreg.x; lo.y = vreg.y;
    uint2 hi; hi.x = vreg.z; hi.y = vreg.w;
    *(uint2*)&Vsl[0][vd1] = lo;
    *(uint2*)&Vsl[0][vd2] = hi;
  }
  __syncthreads();

  for (int sbi = 0; sbi < 8; ++sbi) {
    const int cur = sbi & 1;
    if (sbi < 7) {  // prefetch next 128-s chunk into registers
      int sb = (sbi + 1) * 128;
      kreg = *(const uint4*)&kb[kbase + (size_t)sb * CDIM + kofs];
      vreg = *(const uint4*)&valTb[vbase + sb + vofs];
    }
    const unsigned int* mchunk = mrow + sbi * 64;
#pragma unroll
    for (int ss = 0; ss < 128; ss += 32) {
      const int cb = (ss >> 5) * 1024 + l15 * 32 + quad * 8;
      short8 kf0 = *(const short8*)&Ksl[cur][cb];
      short8 kf1 = *(const short8*)&Ksl[cur][cb + 512];
      short8 vf0 = *(const short8*)&Vsl[cur][cb];
      short8 vf1 = *(const short8*)&Vsl[cur][cb + 512];
      uint2 mk0 = *(const uint2*)&mchunk[(ss >> 1) + quad * 2];
      uint2 mk1 = *(const uint2*)&mchunk[(ss >> 1) + 8 + quad * 2];
      f32x4 s0 = mfma16(kf0, qf, zero4);
      f32x4 s1 = mfma16(kf1, qf, zero4);
      float pa = fexp2(s0[0]), pb = fexp2(s0[1]);
      float pc = fexp2(s0[2]), pd = fexp2(s0[3]);
      float pe = fexp2(s1[0]), pf_ = fexp2(s1[1]);
      float pg = fexp2(s1[2]), ph = fexp2(s1[3]);
      uint4 pu;
      pu.x = pack_bf16(pa, pb) & mk0.x;
      pu.y = pack_bf16(pc, pd) & mk0.y;
      pu.z = pack_bf16(pe, pf_) & mk1.x;
      pu.w = pack_bf16(pg, ph) & mk1.y;
      short8 pfr = *(short8*)&pu;
      o2 = mfma16(pfr, ones, o2);
      o0 = mfma16(pfr, vf0, o0);
      o1 = mfma16(pfr, vf1, o1);
    }
    if (sbi < 7) {
      // write the OTHER buffer (its readers finished before previous barrier)
      const int nxt = cur ^ 1;
      *(uint4*)&Ksl[nxt][kdst] = kreg;
      uint2 lo; lo.x = vreg.x; lo.y = vreg.y;
      uint2 hi; hi.x = vreg.z; hi.y = vreg.w;
      *(uint2*)&Vsl[nxt][vd1] = lo;
      *(uint2*)&Vsl[nxt][vd2] = hi;
    }
    __syncthreads();
  }
  // --- coalesced epilogue: per-wave [16 t][32 d] tile in Ksl ---
  bf16* tile = &Ksl[0][0] + wv * 512;
#pragma unroll
  for (int r = 0; r < 4; ++r) {
    float rli = 1.0f / o2[r];
    int tl = quad * 4 + r;
    tile[tl * 32 + l15] = __float2bfloat16(o0[r] * rli);
    tile[tl * 32 + 16 + l15] = __float2bfloat16(o1[r] * rli);
  }
  {
    int tl = lane >> 2;
    int d8 = (lane & 3) * 8;
    int t = t0w + tl;
    uint4 val = *(const uint4*)&tile[tl * 32 + d8];
    if (t < T_TOK)
      *(uint4*)&ob[((size_t)b * T_TOK + t) * CDIM + h * 32 + d8] = val;
  }
}

// ---------------------------------------------------------------------------
// 4. fused output: delta = o@Wo+bo, gate = tanh(gh@Wg2+bg2),
//    out = bf16(v) + gate*delta -> per-level (b,c,h,w) via LDS transpose.
// ---------------------------------------------------------------------------
__global__ __launch_bounds__(256) void gemm_out(
    const bf16* __restrict__ obuf, const bf16* __restrict__ WoT,
    const float* __restrict__ bo, const bf16* __restrict__ ghb,
    const bf16* __restrict__ Wg2T, const float* __restrict__ bg2,
    const bf16* __restrict__ vTb, float* __restrict__ out, int M) {
  constexpr int HW[5] = {6400, 1600, 400, 100, 25};
  constexpr int TST[5] = {0, 6400, 8000, 8400, 8500};
  constexpr size_t OUTOFF[5] = {0, 3276800, 4096000, 4300800, 4352000};
  __shared__ __align__(16) char smem[52224];
  bf16 (*Asl)[136] = (bf16(*)[136])smem;             // [128][136]
  bf16 (*Bsl)[136] = (bf16(*)[136])(smem + 34816);   // [64][136]
  float (*tile)[132] = (float(*)[132])smem;          // [64][132] (aliases)
  const int tid = threadIdx.x;
  const int wave = tid >> 6, lane = tid & 63, quad = lane >> 4, l15 = lane & 15;
  const int m0 = blockIdx.y * 128, n0 = blockIdx.x * 64;
  f32x4 aD[2][4], aG[2][4];
#pragma unroll
  for (int i = 0; i < 2; ++i)
#pragma unroll
    for (int j = 0; j < 4; ++j) {
      aD[i][j] = (f32x4){0.f, 0.f, 0.f, 0.f};
      aG[i][j] = (f32x4){0.f, 0.f, 0.f, 0.f};
    }
  for (int k0 = 0; k0 < 256; k0 += 128) {
    __syncthreads();
#pragma unroll
    for (int c = 0; c < 8; ++c) {
      int chunk = c * 256 + tid;
      int row = chunk >> 4, col = (chunk & 15) * 8;
      int gr = m0 + row;
      if (gr >= M) gr = M - 1;
      *(uint4*)&Asl[row][col] = *(const uint4*)&obuf[(size_t)gr * 256 + k0 + col];
    }
#pragma unroll
    for (int c = 0; c < 4; ++c) {
      int chunk = c * 256 + tid;
      int row = chunk >> 4, col = (chunk & 15) * 8;
      *(uint4*)&Bsl[row][col] = *(const uint4*)&WoT[(size_t)(n0 + row) * 256 + k0 + col];
    }
    __syncthreads();
#pragma unroll
    for (int kk = 0; kk < 128; kk += 32) {
      short8 af0 = *(const short8*)&Asl[wave * 32 + l15][kk + quad * 8];
      short8 af1 = *(const short8*)&Asl[wave * 32 + 16 + l15][kk + quad * 8];
#pragma unroll
      for (int j = 0; j < 4; ++j) {
        short8 bfj = *(const short8*)&Bsl[j * 16 + l15][kk + quad * 8];
        aD[0][j] = mfma16(af0, bfj, aD[0][j]);
        aD[1][j] = mfma16(af1, bfj, aD[1][j]);
      }
    }
  }
  __syncthreads();
#pragma unroll
  for (int c = 0; c < 8; ++c) {
    int chunk = c * 256 + tid;
    int row = chunk >> 4, col = (chunk & 15) * 8;
    int gr = m0 + row;
    if (gr >= M) gr = M - 1;
    *(uint4*)&Asl[row][col] = *(const uint4*)&ghb[(size_t)gr * 128 + col];
  }
#pragma unroll
  for (int c = 0; c < 4; ++c) {
    int chunk = c * 256 + tid;
    int row = chunk >> 4, col = (chunk & 15) * 8;
    *(uint4*)&Bsl[row][col] = *(const uint4*)&Wg2T[(size_t)(n0 + row) * 128 + col];
  }
  __syncthreads();
#pragma unroll
  for (int kk = 0; kk < 128; kk += 32) {
    short8 af0 = *(const short8*)&Asl[wave * 32 + l15][kk + quad * 8];
    short8 af1 = *(const short8*)&Asl[wave * 32 + 16 + l15][kk + quad * 8];
#pragma unroll
    for (int j = 0; j < 4; ++j) {
      short8 bfj = *(const short8*)&Bsl[j * 16 + l15][kk + quad * 8];
      aG[0][j] = mfma16(af0, bfj, aG[0][j]);
      aG[1][j] = mfma16(af1, bfj, aG[1][j]);
    }
  }
  __syncthreads();  // Asl/Bsl done; smem becomes the transpose tile
#pragma unroll
  for (int ms = 0; ms < 2; ++ms)
#pragma unroll
    for (int nt = 0; nt < 4; ++nt) {
      int n = n0 + nt * 16 + l15;
      float bod = bo[n], bgd = bg2[n];
      float4 res;
      float tmp[4];
#pragma unroll
      for (int r = 0; r < 4; ++r) {
        float xd = aD[ms][nt][r] + bod;
        float xg = aG[ms][nt][r] + bgd;
        float xc = fminf(fmaxf(xg, -15.f), 15.f);
        float e = __expf(2.f * xc);
        float gt = (e - 1.f) / (e + 1.f);
        tmp[r] = gt * xd;
      }
      res.x = tmp[0]; res.y = tmp[1]; res.z = tmp[2]; res.w = tmp[3];
      *(float4*)&tile[nt * 16 + l15][wave * 32 + ms * 16 + quad * 4] = res;
    }
  __syncthreads();
  const int tl = tid & 127, c2 = tid >> 7;
  const int t = m0 + tl;
  const bool valid = t < M;
  int bb = (t >= T_TOK) ? 1 : 0;
  int tt = t - bb * T_TOK;
  if (tt >= T_TOK) tt = T_TOK - 1;
  int lvl = 0;
#pragma unroll
  for (int i = 1; i < 5; ++i) if (tt >= TST[i]) lvl = i;
  const int p = tt - TST[lvl], hw = HW[lvl];
  float* dst = out + OUTOFF[lvl] + ((size_t)bb * CDIM + n0) * hw + p;
  const bf16* vsrc = vTb + ((size_t)bb * CDIM + n0) * T_TOK + tt;
#pragma unroll
  for (int c0 = 0; c0 < 32; ++c0) {
    int c = c0 * 2 + c2;
    if (valid)
      dst[(size_t)c * hw] = __bfloat162float(vsrc[(size_t)c * T_TOK]) + tile[c][tl];
  }
}

// ---------------------------------------------------------------------------
extern "C" void kernel_launch(void* const* d_in, const int* in_sizes, int n_in,
                              void* d_out, int out_size, void* d_ws, size_t ws_size,
                              hipStream_t stream) {
  const float* q0 = (const float*)d_in[0];
  const float* q1 = (const float*)d_in[1];
  const float* q2 = (const float*)d_in[2];
  const float* q3 = (const float*)d_in[3];
  const float* q4 = (const float*)d_in[4];
  const float* cache = (const float*)d_in[5];
  const int* mask = (const int*)d_in[6];
  const float* ln_v_g = (const float*)d_in[7];
  const float* ln_v_b = (const float*)d_in[8];
  const float* ln_c_g = (const float*)d_in[9];
  const float* ln_c_b = (const float*)d_in[10];
  const float* Wv = (const float*)d_in[11];
  const float* bv = (const float*)d_in[12];
  const float* Wc = (const float*)d_in[13];
  const float* bc = (const float*)d_in[14];
  const float* Wvc = (const float*)d_in[15];
  const float* bvc = (const float*)d_in[16];
  const float* Wo = (const float*)d_in[17];
  const float* bo = (const float*)d_in[18];
  const float* Wg1 = (const float*)d_in[19];
  const float* bg1 = (const float*)d_in[20];
  const float* Wg2 = (const float*)d_in[21];
  const float* bg2 = (const float*)d_in[22];
  float* out = (float*)d_out;

  const int R = BSZ * T_TOK;              // 17050 rows
  const size_t RC = (size_t)R * CDIM;
  const size_t SC = (size_t)BSZ * S_TOK * CDIM;

  char* p = (char*)d_ws;
  bf16* vTb = (bf16*)p;            p += RC * 2;
  bf16* vb = (bf16*)p;             p += RC * 2;
  bf16* vnb = (bf16*)p;            p += RC * 2;
  bf16* qb = (bf16*)p;             p += RC * 2;
  bf16* ob = (bf16*)p;             p += RC * 2;
  bf16* ghb = (bf16*)p;            p += (size_t)R * 128 * 2;
  bf16* cnb = (bf16*)p;            p += SC * 2;
  bf16* kb = (bf16*)p;             p += SC * 2;
  bf16* valTb = (bf16*)p;          p += SC * 2;
  bf16* WqgT = (bf16*)p;           p += 98304 * 2;   // [Wv(256); Wg1(128)] x 256
  bf16* WcvcT = (bf16*)p;          p += 131072 * 2;
  bf16* WoT = (bf16*)p;            p += 65536 * 2;
  bf16* Wg2T = (bf16*)p;           p += 32768 * 2;
  float* biasCV = (float*)p;       p += 512 * 4;
  float* biasQG = (float*)p;       p += 384 * 4;
  unsigned int* mpk = (unsigned int*)p; p += 1024 * 4;

  stage1<<<dim3(1661), dim3(256), 0, stream>>>(
      q0, q1, q2, q3, q4, Wv, Wc, Wvc, Wo, Wg1, Wg2, bv, bg1, bc, bvc,
      cache, mask, ln_c_g, ln_c_b, ln_v_g, ln_v_b,
      WqgT, WcvcT, WoT, Wg2T, biasCV, biasQG, mpk, cnb, vTb, vb, vnb);
  gemm_fused<<<dim3(932), dim3(256), 0, stream>>>(
      vnb, vb, WqgT, biasQG, qb, ghb, cnb, WcvcT, biasCV, kb, valTb);
  attn_kernel<<<dim3(67, BSZ * NHEAD), dim3(512), 0, stream>>>(
      qb, kb, valTb, mpk, ob);
  gemm_out<<<dim3(4, 134), dim3(256), 0, stream>>>(
      ob, WoT, bo, ghb, Wg2T, bg2, vTb, out, R);
}